// Round 5
// baseline (1996.180 us; speedup 1.0000x reference)
//
#include <hip/hip_runtime.h>
#include <stdint.h>

#define NT   8192
#define DI   2048
#define DH   16384
#define DO   2048
#define KSEL 64
#define EPS_SEL 0.004f
#define BCAP 256
#define KSTEPS 64   // K=2048 / BK=32 for both GEMMs

typedef _Float16 f16;
typedef f16  f16x8 __attribute__((ext_vector_type(8)));
typedef float f32x4 __attribute__((ext_vector_type(4)));
typedef unsigned short usx8 __attribute__((ext_vector_type(8)));

__device__ __forceinline__ unsigned short f2h_bits(float x){
  f16 h = (f16)x;
  union { f16 h; unsigned short u; } c; c.h = h; return c.u;
}
__device__ __forceinline__ float h_bits2f(unsigned short u){
  union { unsigned short u; f16 h; } c; c.u = u; return (float)c.h;
}

__device__ __forceinline__ void gload16(const void* g, void* lds){
  __builtin_amdgcn_global_load_lds(
    (const __attribute__((address_space(1))) void*)(uintptr_t)g,
    (__attribute__((address_space(3))) void*)(uint32_t)(uintptr_t)lds,
    16, 0, 0);
}

// ---------------- f32 -> f16 convert (vector8) ----------------
__global__ __launch_bounds__(256) void k_cvt(const float* __restrict__ in,
                                             unsigned short* __restrict__ out, int n8)
{
  int i = blockIdx.x*256 + threadIdx.x;
  if (i >= n8) return;
  const float4* p = (const float4*)in + (size_t)i*2;
  float4 a = p[0], b = p[1];
  union { f16 h[8]; usx8 u; } r;
  r.h[0]=(f16)a.x; r.h[1]=(f16)a.y; r.h[2]=(f16)a.z; r.h[3]=(f16)a.w;
  r.h[4]=(f16)b.x; r.h[5]=(f16)b.y; r.h[6]=(f16)b.z; r.h[7]=(f16)b.w;
  ((usx8*)out)[i] = r.u;
}

// ---------------- W_dec [DO][DH] f32 -> WdecT [DH][DO] f16 ----------------
__global__ __launch_bounds__(256) void k_transpose_cvt(const float* __restrict__ W,
                                                       unsigned short* __restrict__ WT)
{
  __shared__ unsigned short t[64][65];
  const int r0 = blockIdx.x*64;   // over DO
  const int c0 = blockIdx.y*64;   // over DH
  const int tid = threadIdx.x;
  const int q = tid >> 6, s = tid & 63;
#pragma unroll
  for (int i=0;i<16;i++){
    int r = q + i*4;
    t[r][s] = f2h_bits(W[(size_t)(r0+r)*DH + c0 + s]);
  }
  __syncthreads();
#pragma unroll
  for (int i=0;i<16;i++){
    int c = q + i*4;
    WT[(size_t)(c0+c)*DO + r0 + s] = t[s][c];
  }
}

// ---------------- f16 MFMA GEMM: C[M][N] = A[M][K] * B[N][K]^T + bias ----------------
// 2-phase double-buffered pipeline (T3-minimum). XCD partition (fixed from R3):
// each XCD owns a contiguous *bn band* (gridN/8 panels, B band = 1-8MB -> L2/L3
// resident, fetched from HBM once) and iterates bm FASTEST within the band, so
// concurrent blocks on one XCD share 1-2 B panels (0.5-1MB, L2) while A (32MB)
// is L3-resident shared across all XCDs. Requires gridM == 64.
template<bool F16OUT>
__global__ __launch_bounds__(256) void k_gemm(
    const unsigned short* __restrict__ A,
    const unsigned short* __restrict__ B,
    const float* __restrict__ bias1,
    const float* __restrict__ bias2,
    void* __restrict__ Cout,
    int N, int Kd, int gridN)
{
  __shared__ unsigned short lA[2][128*32];
  __shared__ unsigned short lB[2][128*32];
  const int tid  = threadIdx.x;
  const int lane = tid & 63;
  const int wv   = tid >> 6;

  // XCD-band mapping: hardware XCD = blockIdx.x % 8 (round-robin dispatch).
  const int xcd = blockIdx.x & 7;
  const int idx = blockIdx.x >> 3;
  const int bm  = idx & 63;                        // bm fastest (gridM == 64)
  const int bn  = xcd * (gridN >> 3) + (idx >> 6); // contiguous bn band per XCD

  const int wm   = wv >> 1, wn = wv & 1;

  f32x4 acc[4][4];
#pragma unroll
  for (int m=0;m<4;m++)
#pragma unroll
    for (int n=0;n<4;n++) acc[m][n] = (f32x4){0.f,0.f,0.f,0.f};

  // staging source: quad = one row's 64B, 16 rows per wave-issue (coalesced)
  const int lr  = lane >> 2;         // local row 0..15
  const int kq4 = lane & 3;          // 16B chunk within row
  const unsigned short* gA = A + (size_t)(bm*128 + wv*16 + lr)*Kd + kq4*8;
  const unsigned short* gB = B + (size_t)(bn*128 + wv*16 + lr)*Kd + kq4*8;

#define STAGE(BUF, KS) do { \
    const int _ko = (KS)*32; \
    gload16(gA + _ko,                  &lA[BUF][wv*512]); \
    gload16(gA + _ko + (size_t)64*Kd,  &lA[BUF][2048 + wv*512]); \
    gload16(gB + _ko,                  &lB[BUF][wv*512]); \
    gload16(gB + _ko + (size_t)64*Kd,  &lB[BUF][2048 + wv*512]); \
  } while(0)

#define COMPUTE(BUF) do { \
    const int kq = (lane >> 4) * 8; \
    const int rr = lane & 15; \
    f16x8 af[4], bf[4]; \
    _Pragma("unroll") \
    for (int m=0;m<4;m++) \
      af[m] = *(const f16x8*)&lA[BUF][(wm*64 + m*16 + rr)*32 + kq]; \
    _Pragma("unroll") \
    for (int n=0;n<4;n++) \
      bf[n] = *(const f16x8*)&lB[BUF][(wn*64 + n*16 + rr)*32 + kq]; \
    _Pragma("unroll") \
    for (int m=0;m<4;m++) \
      _Pragma("unroll") \
      for (int n=0;n<4;n++) \
        acc[m][n] = __builtin_amdgcn_mfma_f32_16x16x32_f16(af[m], bf[n], acc[m][n], 0, 0, 0); \
  } while(0)

  STAGE(0, 0);
  __syncthreads();
  for (int e = 0; e < KSTEPS-2; e += 2) {
    STAGE(1, e+1); COMPUTE(0); __syncthreads();
    STAGE(0, e+2); COMPUTE(1); __syncthreads();
  }
  STAGE(1, KSTEPS-1); COMPUTE(0); __syncthreads();
  COMPUTE(1);

#undef STAGE
#undef COMPUTE

  const int rowBase = bm*128 + wm*64 + ((lane>>4)<<2);
  const int colBase = bn*128 + wn*64 + (lane & 15);
#pragma unroll
  for (int n=0;n<4;n++) {
    const int col = colBase + n*16;
    float bs = bias1[col];
    if (bias2) bs += bias2[col];
#pragma unroll
    for (int m=0;m<4;m++) {
#pragma unroll
      for (int q=0;q<4;q++) {
        const int row = rowBase + m*16 + q;
        float v = acc[m][n][q] + bs;
        if (F16OUT) ((unsigned short*)Cout)[(size_t)row*N + col] = f2h_bits(v);
        else        ((float*)Cout)[(size_t)row*N + col] = v;
      }
    }
  }
}

// ---------------- exact top-64 per row ----------------
__global__ __launch_bounds__(256) void k_topk(
    const unsigned short* __restrict__ P,   // f16 preacts [NT][DH]
    const float* __restrict__ X,            // [NT][DI] f32
    const float* __restrict__ Wenc,         // [DH][DI] f32
    const float* __restrict__ benc,         // [DH]
    int*   __restrict__ candIdx,            // [NT][KSEL]
    float* __restrict__ candVal)
{
  __shared__ unsigned short row[DH];
  __shared__ unsigned int hist[256];
  __shared__ int inIdx[64];
  __shared__ int bandIdx[BCAP];
  __shared__ double bandVal[BCAP];
  __shared__ unsigned char bandUsed[BCAP];
  __shared__ int s_inCnt, s_bandCnt, s_bsel, s_cntAbove;
  __shared__ float s_T;

  const int r = blockIdx.x;
  const int tid = threadIdx.x;
  const unsigned short* Prow = P + (size_t)r*DH;

  for (int i=tid; i<DH/8; i+=256) ((usx8*)row)[i] = ((const usx8*)Prow)[i];
  hist[tid & 255] = 0;
  if (tid==0){ s_inCnt=0; s_bandCnt=0; }
  __syncthreads();

  // radix pass 1: high byte of order-mapped u16
  for (int i=tid;i<DH;i+=256){
    unsigned short b = row[i];
    unsigned short o = (b & 0x8000) ? (unsigned short)~b : (unsigned short)(b|0x8000);
    atomicAdd(&hist[o>>8], 1u);
  }
  __syncthreads();
  if (tid==0){
    int cum=0, bsel=0;
    for (int h=255; h>=0; h--){
      if (cum + (int)hist[h] >= KSEL){ bsel=h; break; }
      cum += hist[h];
    }
    s_bsel = bsel; s_cntAbove = cum;
  }
  __syncthreads();
  const int bsel = s_bsel; const int cntAbove = s_cntAbove;
  hist[tid & 255] = 0;
  __syncthreads();
  // radix pass 2: low byte within bucket
  for (int i=tid;i<DH;i+=256){
    unsigned short b = row[i];
    unsigned short o = (b & 0x8000) ? (unsigned short)~b : (unsigned short)(b|0x8000);
    if ((int)(o>>8)==bsel) atomicAdd(&hist[o&0xff],1u);
  }
  __syncthreads();
  if (tid==0){
    int cum = cntAbove, lsel = 0;
    for (int h=255; h>=0; h--){
      if (cum + (int)hist[h] >= KSEL){ lsel=h; break; }
      cum += hist[h];
    }
    unsigned short To = (unsigned short)((bsel<<8) | lsel);
    unsigned short tb = (To & 0x8000) ? (unsigned short)(To ^ 0x8000) : (unsigned short)~To;
    s_T = h_bits2f(tb);
  }
  __syncthreads();
  const float T = s_T;
  const float hiv = T + 2.0f*EPS_SEL, lov = T - 2.0f*EPS_SEL;

  for (int i=tid;i<DH;i+=256){
    float v = h_bits2f(row[i]);
    if (v > hiv){
      int p = atomicAdd(&s_inCnt,1);
      if (p < 64) inIdx[p] = i;
    } else if (v >= lov){
      int p = atomicAdd(&s_bandCnt,1);
      if (p < BCAP) bandIdx[p] = i;
    }
  }
  __syncthreads();
  const int m = s_inCnt < 64 ? s_inCnt : 64;
  const int B = s_bandCnt < BCAP ? s_bandCnt : BCAP;

  // exact f64 recompute for ambiguous band (from original f32 inputs)
  const int wv = tid>>6, lane = tid&63;
  const float* Xr = X + (size_t)r*DI;
  for (int b=wv; b<B; b+=4){
    const int j = bandIdx[b];
    const float* Wr = Wenc + (size_t)j*DI;
    double s = 0.0;
    for (int k=lane; k<DI; k+=64)
      s = fma((double)Xr[k], (double)Wr[k], s);
#pragma unroll
    for (int off=32; off>=1; off>>=1) s += __shfl_down(s, off);
    if (lane==0) bandVal[b] = s + (double)benc[j];
  }
  for (int i=tid;i<BCAP;i+=256) bandUsed[i]=0;

  int* ci = candIdx + (size_t)r*KSEL;
  float* cv = candVal + (size_t)r*KSEL;
  for (int t=tid; t<m; t+=256){
    int j = inIdx[t];
    ci[t]=j; cv[t]=h_bits2f(row[j]);
  }
  __syncthreads();
  if (tid==0){
    int need = KSEL - m;
    for (int t=0;t<need;t++){
      double best=-1e300; int bi=0;
      for (int b=0;b<B;b++)
        if (!bandUsed[b] && bandVal[b]>best){ best=bandVal[b]; bi=b; }
      bandUsed[bi]=1;
      ci[m+t]=bandIdx[bi]; cv[m+t]=(float)best;
    }
  }
}

// ---------------- sparse decode + loss partial ----------------
__global__ __launch_bounds__(256) void k_decode(
    float* __restrict__ outhat,              // [NT][DO], holds skip part
    const unsigned short* __restrict__ WdT,  // f16 [DH][DO]
    const int*   __restrict__ candIdx,
    const float* __restrict__ candVal,
    const float* __restrict__ target,
    float* __restrict__ lossPartial)
{
  __shared__ int   sIdx[KSEL];
  __shared__ float sVal[KSEL];
  __shared__ float wsum[4];
  const int r = blockIdx.x, tid = threadIdx.x;
  if (tid < KSEL){
    sIdx[tid]=candIdx[(size_t)r*KSEL+tid];
    float v=candVal[(size_t)r*KSEL+tid];
    sVal[tid] = v>0.f ? v : 0.f;
  }
  __syncthreads();
  float* orow = outhat + (size_t)r*DO;
  float a[8];
  {
    float4 v0 = *(const float4*)(orow + tid*8);
    float4 v1 = *(const float4*)(orow + tid*8 + 4);
    a[0]=v0.x;a[1]=v0.y;a[2]=v0.z;a[3]=v0.w;a[4]=v1.x;a[5]=v1.y;a[6]=v1.z;a[7]=v1.w;
  }
  for (int c=0;c<KSEL;c++){
    const float v = sVal[c];
    if (v==0.f) continue;
    const f16x8 w = *(const f16x8*)(WdT + (size_t)sIdx[c]*DO + tid*8);
#pragma unroll
    for (int j=0;j<8;j++) a[j] = fmaf(v, (float)w[j], a[j]);
  }
  const float* trow = target + (size_t)r*DO;
  float4 t0 = *(const float4*)(trow + tid*8);
  float4 t1 = *(const float4*)(trow + tid*8 + 4);
  float tt[8] = {t0.x,t0.y,t0.z,t0.w,t1.x,t1.y,t1.z,t1.w};
  float ls = 0.f;
#pragma unroll
  for (int j=0;j<8;j++){ float d = a[j]-tt[j]; ls = fmaf(d,d,ls); }
  {
    float4 v0 = {a[0],a[1],a[2],a[3]}, v1 = {a[4],a[5],a[6],a[7]};
    *(float4*)(orow + tid*8) = v0;
    *(float4*)(orow + tid*8 + 4) = v1;
  }
#pragma unroll
  for (int off=32; off>=1; off>>=1) ls += __shfl_down(ls, off);
  if ((tid&63)==0) wsum[tid>>6]=ls;
  __syncthreads();
  if (tid==0)
    lossPartial[r] = (wsum[0]+wsum[1]+wsum[2]+wsum[3]) * (1.0f/((float)NT*(float)DO));
}

__global__ __launch_bounds__(256) void k_lossreduce(const float* __restrict__ lp,
                                                    float* __restrict__ out)
{
  __shared__ double ws[4];
  double s=0.0;
  for (int i=threadIdx.x;i<NT;i+=256) s += (double)lp[i];
#pragma unroll
  for (int off=32; off>=1; off>>=1) s += __shfl_down(s, off);
  if ((threadIdx.x&63)==0) ws[threadIdx.x>>6]=s;
  __syncthreads();
  if (threadIdx.x==0) *out = (float)(ws[0]+ws[1]+ws[2]+ws[3]);
}

// ---------------- finalize h: zero + scatter ----------------
__global__ __launch_bounds__(256) void k_scatter(
    float* __restrict__ H, const int* __restrict__ candIdx, const float* __restrict__ candVal)
{
  const int r=blockIdx.x, tid=threadIdx.x;
  float* hr = H + (size_t)r*DH;
  const float4 z = {0.f,0.f,0.f,0.f};
#pragma unroll
  for (int i=0;i<16;i++) ((float4*)hr)[tid + i*256] = z;
  __syncthreads();
  if (tid<KSEL){
    float v = candVal[(size_t)r*KSEL+tid];
    hr[candIdx[(size_t)r*KSEL+tid]] = v>0.f ? v : 0.f;
  }
}

extern "C" void kernel_launch(void* const* d_in, const int* in_sizes, int n_in,
                              void* d_out, int out_size, void* d_ws, size_t ws_size,
                              hipStream_t stream)
{
  const float* X     = (const float*)d_in[0];
  const float* tgt   = (const float*)d_in[1];
  const float* Wenc  = (const float*)d_in[2];
  const float* benc  = (const float*)d_in[3];
  const float* Wdec  = (const float*)d_in[4];
  const float* bdec  = (const float*)d_in[5];
  const float* Wskip = (const float*)d_in[6];
  const float* bskip = (const float*)d_in[7];

  float* out     = (float*)d_out;
  float* outhat  = out;
  float* H       = out + (size_t)NT*DO;
  float* lossOut = out + (size_t)NT*DO + (size_t)NT*DH;

  // h-region scratch plan (dead until k_scatter):
  //   [0, 2^28)        : f16 pre-acts
  //   [2^28, ...)      : f16 copies of X, W_enc, W_skip, W_dec^T
  char* hb = (char*)H;
  unsigned short* P      = (unsigned short*)hb;
  char* U                = hb + (size_t)NT*DH*2;
  unsigned short* Xh     = (unsigned short*)U;
  unsigned short* Wench  = (unsigned short*)(U + (size_t)NT*DI*2);
  unsigned short* Wskiph = (unsigned short*)(U + (size_t)NT*DI*2 + (size_t)DH*DI*2);
  unsigned short* WdTh   = (unsigned short*)(U + (size_t)NT*DI*2 + (size_t)DH*DI*2 + (size_t)DO*DI*2);

  // ws: candidate lists must survive the h overwrite
  int*   candIdx    = (int*)d_ws;
  float* candVal    = (float*)((char*)d_ws + (size_t)NT*KSEL*4);
  float* lossPartial= (float*)((char*)d_ws + (size_t)NT*KSEL*8);

  k_cvt<<<NT*DI/8/256, 256, 0, stream>>>(X, Xh, NT*DI/8);
  k_cvt<<<DH*DI/8/256, 256, 0, stream>>>(Wenc, Wench, DH*DI/8);
  k_cvt<<<DO*DI/8/256, 256, 0, stream>>>(Wskip, Wskiph, DO*DI/8);
  k_transpose_cvt<<<dim3(DO/64, DH/64), 256, 0, stream>>>(Wdec, WdTh);

  k_gemm<true ><<<(NT/128)*(DH/128), 256, 0, stream>>>(Xh, Wench, benc, nullptr, (void*)P, DH, DI, DH/128);
  k_topk<<<NT, 256, 0, stream>>>(P, X, Wenc, benc, candIdx, candVal);
  k_gemm<false><<<(NT/128)*(DO/128), 256, 0, stream>>>(Xh, Wskiph, bdec, bskip, (void*)outhat, DO, DI, DO/128);
  k_decode<<<NT, 256, 0, stream>>>(outhat, WdTh, candIdx, candVal, tgt, lossPartial);
  k_lossreduce<<<1, 256, 0, stream>>>(lossPartial, lossOut);
  k_scatter<<<NT, 256, 0, stream>>>(H, candIdx, candVal);
}

// Round 6
// 1951.999 us; speedup vs baseline: 1.0226x; 1.0226x over previous
//
#include <hip/hip_runtime.h>
#include <stdint.h>

#define NT   8192
#define DI   2048
#define DH   16384
#define DO   2048
#define KSEL 64
#define EPS_SEL 0.004f
#define BCAP 256
#define KSTEPS 64   // K=2048 / BK=32 for both GEMMs

typedef _Float16 f16;
typedef f16  f16x8 __attribute__((ext_vector_type(8)));
typedef float f32x4 __attribute__((ext_vector_type(4)));
typedef unsigned short usx8 __attribute__((ext_vector_type(8)));

__device__ __forceinline__ unsigned short f2h_bits(float x){
  f16 h = (f16)x;
  union { f16 h; unsigned short u; } c; c.h = h; return c.u;
}
__device__ __forceinline__ float h_bits2f(unsigned short u){
  union { unsigned short u; f16 h; } c; c.u = u; return (float)c.h;
}

__device__ __forceinline__ void gload16(const void* g, void* lds){
  __builtin_amdgcn_global_load_lds(
    (const __attribute__((address_space(1))) void*)(uintptr_t)g,
    (__attribute__((address_space(3))) void*)(uint32_t)(uintptr_t)lds,
    16, 0, 0);
}

// ---------------- f32 -> f16 convert (vector8) ----------------
__global__ __launch_bounds__(256) void k_cvt(const float* __restrict__ in,
                                             unsigned short* __restrict__ out, int n8)
{
  int i = blockIdx.x*256 + threadIdx.x;
  if (i >= n8) return;
  const float4* p = (const float4*)in + (size_t)i*2;
  float4 a = p[0], b = p[1];
  union { f16 h[8]; usx8 u; } r;
  r.h[0]=(f16)a.x; r.h[1]=(f16)a.y; r.h[2]=(f16)a.z; r.h[3]=(f16)a.w;
  r.h[4]=(f16)b.x; r.h[5]=(f16)b.y; r.h[6]=(f16)b.z; r.h[7]=(f16)b.w;
  ((usx8*)out)[i] = r.u;
}

// ---------------- W_dec [DO][DH] f32 -> WdecT [DH][DO] f16 ----------------
__global__ __launch_bounds__(256) void k_transpose_cvt(const float* __restrict__ W,
                                                       unsigned short* __restrict__ WT)
{
  __shared__ unsigned short t[64][65];
  const int r0 = blockIdx.x*64;   // over DO
  const int c0 = blockIdx.y*64;   // over DH
  const int tid = threadIdx.x;
  const int q = tid >> 6, s = tid & 63;
#pragma unroll
  for (int i=0;i<16;i++){
    int r = q + i*4;
    t[r][s] = f2h_bits(W[(size_t)(r0+r)*DH + c0 + s]);
  }
  __syncthreads();
#pragma unroll
  for (int i=0;i<16;i++){
    int c = q + i*4;
    WT[(size_t)(c0+c)*DO + r0 + s] = t[s][c];
  }
}

// ---------------- f16 MFMA GEMM body: C[M][N] = A[M][K]*B[N][K]^T + bias ----------
// R0's proven grid mapping (2D: bm = blockIdx.x fastest -> consecutive dispatch
// shares one B panel, HW round-robin over XCDs gave FETCH 0.68 GB) + 2-phase
// double-buffered pipeline (R3's proven +12% on dur). Static buffer indices.
template<bool F16OUT>
__device__ __forceinline__ void gemm_body(
    const unsigned short* __restrict__ A,
    const unsigned short* __restrict__ B,
    const float* __restrict__ bias1,
    const float* __restrict__ bias2,
    void* __restrict__ Cout,
    int N, int Kd)
{
  __shared__ unsigned short lA[2][128*32];
  __shared__ unsigned short lB[2][128*32];
  const int tid  = threadIdx.x;
  const int lane = tid & 63;
  const int wv   = tid >> 6;
  const int bm   = blockIdx.x, bn = blockIdx.y;
  const int wm   = wv >> 1, wn = wv & 1;

  f32x4 acc[4][4];
#pragma unroll
  for (int m=0;m<4;m++)
#pragma unroll
    for (int n=0;n<4;n++) acc[m][n] = (f32x4){0.f,0.f,0.f,0.f};

  // staging source: quad = one row's 64B, 16 rows per wave-issue (coalesced)
  const int lr  = lane >> 2;         // local row 0..15
  const int kq4 = lane & 3;          // 16B chunk within row
  const unsigned short* gA = A + (size_t)(bm*128 + wv*16 + lr)*Kd + kq4*8;
  const unsigned short* gB = B + (size_t)(bn*128 + wv*16 + lr)*Kd + kq4*8;

#define STAGE(BUF, KS) do { \
    const int _ko = (KS)*32; \
    gload16(gA + _ko,                  &lA[BUF][wv*512]); \
    gload16(gA + _ko + (size_t)64*Kd,  &lA[BUF][2048 + wv*512]); \
    gload16(gB + _ko,                  &lB[BUF][wv*512]); \
    gload16(gB + _ko + (size_t)64*Kd,  &lB[BUF][2048 + wv*512]); \
  } while(0)

#define COMPUTE(BUF) do { \
    const int kq = (lane >> 4) * 8; \
    const int rr = lane & 15; \
    f16x8 af[4], bf[4]; \
    _Pragma("unroll") \
    for (int m=0;m<4;m++) \
      af[m] = *(const f16x8*)&lA[BUF][(wm*64 + m*16 + rr)*32 + kq]; \
    _Pragma("unroll") \
    for (int n=0;n<4;n++) \
      bf[n] = *(const f16x8*)&lB[BUF][(wn*64 + n*16 + rr)*32 + kq]; \
    _Pragma("unroll") \
    for (int m=0;m<4;m++) \
      _Pragma("unroll") \
      for (int n=0;n<4;n++) \
        acc[m][n] = __builtin_amdgcn_mfma_f32_16x16x32_f16(af[m], bf[n], acc[m][n], 0, 0, 0); \
  } while(0)

  STAGE(0, 0);
  __syncthreads();
  for (int e = 0; e < KSTEPS-2; e += 2) {
    STAGE(1, e+1); COMPUTE(0); __syncthreads();
    STAGE(0, e+2); COMPUTE(1); __syncthreads();
  }
  STAGE(1, KSTEPS-1); COMPUTE(0); __syncthreads();
  COMPUTE(1);

#undef STAGE
#undef COMPUTE

  const int rowBase = bm*128 + wm*64 + ((lane>>4)<<2);
  const int colBase = bn*128 + wn*64 + (lane & 15);
#pragma unroll
  for (int n=0;n<4;n++) {
    const int col = colBase + n*16;
    float bs = bias1[col];
    if (bias2) bs += bias2[col];
#pragma unroll
    for (int m=0;m<4;m++) {
#pragma unroll
      for (int q=0;q<4;q++) {
        const int row = rowBase + m*16 + q;
        float v = acc[m][n][q] + bs;
        if (F16OUT) ((unsigned short*)Cout)[(size_t)row*N + col] = f2h_bits(v);
        else        ((float*)Cout)[(size_t)row*N + col] = v;
      }
    }
  }
}

__global__ __launch_bounds__(256) void k_gemm_enc(
    const unsigned short* __restrict__ A, const unsigned short* __restrict__ B,
    const float* __restrict__ bias1, void* __restrict__ Cout)
{
  gemm_body<true>(A, B, bias1, nullptr, Cout, DH, DI);
}

__global__ __launch_bounds__(256) void k_gemm_skip(
    const unsigned short* __restrict__ A, const unsigned short* __restrict__ B,
    const float* __restrict__ bias1, const float* __restrict__ bias2,
    void* __restrict__ Cout)
{
  gemm_body<false>(A, B, bias1, bias2, Cout, DO, DI);
}

// ---------------- exact top-64 per row ----------------
__global__ __launch_bounds__(256) void k_topk(
    const unsigned short* __restrict__ P,   // f16 preacts [NT][DH]
    const float* __restrict__ X,            // [NT][DI] f32
    const float* __restrict__ Wenc,         // [DH][DI] f32
    const float* __restrict__ benc,         // [DH]
    int*   __restrict__ candIdx,            // [NT][KSEL]
    float* __restrict__ candVal)
{
  __shared__ unsigned short row[DH];
  __shared__ unsigned int hist[256];
  __shared__ int inIdx[64];
  __shared__ int bandIdx[BCAP];
  __shared__ double bandVal[BCAP];
  __shared__ unsigned char bandUsed[BCAP];
  __shared__ int s_inCnt, s_bandCnt, s_bsel, s_cntAbove;
  __shared__ float s_T;

  const int r = blockIdx.x;
  const int tid = threadIdx.x;
  const unsigned short* Prow = P + (size_t)r*DH;

  for (int i=tid; i<DH/8; i+=256) ((usx8*)row)[i] = ((const usx8*)Prow)[i];
  hist[tid & 255] = 0;
  if (tid==0){ s_inCnt=0; s_bandCnt=0; }
  __syncthreads();

  // radix pass 1: high byte of order-mapped u16
  for (int i=tid;i<DH;i+=256){
    unsigned short b = row[i];
    unsigned short o = (b & 0x8000) ? (unsigned short)~b : (unsigned short)(b|0x8000);
    atomicAdd(&hist[o>>8], 1u);
  }
  __syncthreads();
  if (tid==0){
    int cum=0, bsel=0;
    for (int h=255; h>=0; h--){
      if (cum + (int)hist[h] >= KSEL){ bsel=h; break; }
      cum += hist[h];
    }
    s_bsel = bsel; s_cntAbove = cum;
  }
  __syncthreads();
  const int bsel = s_bsel; const int cntAbove = s_cntAbove;
  hist[tid & 255] = 0;
  __syncthreads();
  // radix pass 2: low byte within bucket
  for (int i=tid;i<DH;i+=256){
    unsigned short b = row[i];
    unsigned short o = (b & 0x8000) ? (unsigned short)~b : (unsigned short)(b|0x8000);
    if ((int)(o>>8)==bsel) atomicAdd(&hist[o&0xff],1u);
  }
  __syncthreads();
  if (tid==0){
    int cum = cntAbove, lsel = 0;
    for (int h=255; h>=0; h--){
      if (cum + (int)hist[h] >= KSEL){ lsel=h; break; }
      cum += hist[h];
    }
    unsigned short To = (unsigned short)((bsel<<8) | lsel);
    unsigned short tb = (To & 0x8000) ? (unsigned short)(To ^ 0x8000) : (unsigned short)~To;
    s_T = h_bits2f(tb);
  }
  __syncthreads();
  const float T = s_T;
  const float hiv = T + 2.0f*EPS_SEL, lov = T - 2.0f*EPS_SEL;

  for (int i=tid;i<DH;i+=256){
    float v = h_bits2f(row[i]);
    if (v > hiv){
      int p = atomicAdd(&s_inCnt,1);
      if (p < 64) inIdx[p] = i;
    } else if (v >= lov){
      int p = atomicAdd(&s_bandCnt,1);
      if (p < BCAP) bandIdx[p] = i;
    }
  }
  __syncthreads();
  const int m = s_inCnt < 64 ? s_inCnt : 64;
  const int B = s_bandCnt < BCAP ? s_bandCnt : BCAP;

  // exact f64 recompute for ambiguous band (from original f32 inputs)
  const int wv = tid>>6, lane = tid&63;
  const float* Xr = X + (size_t)r*DI;
  for (int b=wv; b<B; b+=4){
    const int j = bandIdx[b];
    const float* Wr = Wenc + (size_t)j*DI;
    double s = 0.0;
    for (int k=lane; k<DI; k+=64)
      s = fma((double)Xr[k], (double)Wr[k], s);
#pragma unroll
    for (int off=32; off>=1; off>>=1) s += __shfl_down(s, off);
    if (lane==0) bandVal[b] = s + (double)benc[j];
  }
  for (int i=tid;i<BCAP;i+=256) bandUsed[i]=0;

  int* ci = candIdx + (size_t)r*KSEL;
  float* cv = candVal + (size_t)r*KSEL;
  for (int t=tid; t<m; t+=256){
    int j = inIdx[t];
    ci[t]=j; cv[t]=h_bits2f(row[j]);
  }
  __syncthreads();
  if (tid==0){
    int need = KSEL - m;
    for (int t=0;t<need;t++){
      double best=-1e300; int bi=0;
      for (int b=0;b<B;b++)
        if (!bandUsed[b] && bandVal[b]>best){ best=bandVal[b]; bi=b; }
      bandUsed[bi]=1;
      ci[m+t]=bandIdx[bi]; cv[m+t]=(float)best;
    }
  }
}

// ---------------- sparse decode + loss partial ----------------
__global__ __launch_bounds__(256) void k_decode(
    float* __restrict__ outhat,              // [NT][DO], holds skip part
    const unsigned short* __restrict__ WdT,  // f16 [DH][DO]
    const int*   __restrict__ candIdx,
    const float* __restrict__ candVal,
    const float* __restrict__ target,
    float* __restrict__ lossPartial)
{
  __shared__ int   sIdx[KSEL];
  __shared__ float sVal[KSEL];
  __shared__ float wsum[4];
  const int r = blockIdx.x, tid = threadIdx.x;
  if (tid < KSEL){
    sIdx[tid]=candIdx[(size_t)r*KSEL+tid];
    float v=candVal[(size_t)r*KSEL+tid];
    sVal[tid] = v>0.f ? v : 0.f;
  }
  __syncthreads();
  float* orow = outhat + (size_t)r*DO;
  float a[8];
  {
    float4 v0 = *(const float4*)(orow + tid*8);
    float4 v1 = *(const float4*)(orow + tid*8 + 4);
    a[0]=v0.x;a[1]=v0.y;a[2]=v0.z;a[3]=v0.w;a[4]=v1.x;a[5]=v1.y;a[6]=v1.z;a[7]=v1.w;
  }
  for (int c=0;c<KSEL;c++){
    const float v = sVal[c];
    if (v==0.f) continue;
    const f16x8 w = *(const f16x8*)(WdT + (size_t)sIdx[c]*DO + tid*8);
#pragma unroll
    for (int j=0;j<8;j++) a[j] = fmaf(v, (float)w[j], a[j]);
  }
  const float* trow = target + (size_t)r*DO;
  float4 t0 = *(const float4*)(trow + tid*8);
  float4 t1 = *(const float4*)(trow + tid*8 + 4);
  float tt[8] = {t0.x,t0.y,t0.z,t0.w,t1.x,t1.y,t1.z,t1.w};
  float ls = 0.f;
#pragma unroll
  for (int j=0;j<8;j++){ float d = a[j]-tt[j]; ls = fmaf(d,d,ls); }
  {
    float4 v0 = {a[0],a[1],a[2],a[3]}, v1 = {a[4],a[5],a[6],a[7]};
    *(float4*)(orow + tid*8) = v0;
    *(float4*)(orow + tid*8 + 4) = v1;
  }
#pragma unroll
  for (int off=32; off>=1; off>>=1) ls += __shfl_down(ls, off);
  if ((tid&63)==0) wsum[tid>>6]=ls;
  __syncthreads();
  if (tid==0)
    lossPartial[r] = (wsum[0]+wsum[1]+wsum[2]+wsum[3]) * (1.0f/((float)NT*(float)DO));
}

__global__ __launch_bounds__(256) void k_lossreduce(const float* __restrict__ lp,
                                                    float* __restrict__ out)
{
  __shared__ double ws[4];
  double s=0.0;
  for (int i=threadIdx.x;i<NT;i+=256) s += (double)lp[i];
#pragma unroll
  for (int off=32; off>=1; off>>=1) s += __shfl_down(s, off);
  if ((threadIdx.x&63)==0) ws[threadIdx.x>>6]=s;
  __syncthreads();
  if (threadIdx.x==0) *out = (float)(ws[0]+ws[1]+ws[2]+ws[3]);
}

// ---------------- finalize h: zero + scatter ----------------
__global__ __launch_bounds__(256) void k_scatter(
    float* __restrict__ H, const int* __restrict__ candIdx, const float* __restrict__ candVal)
{
  const int r=blockIdx.x, tid=threadIdx.x;
  float* hr = H + (size_t)r*DH;
  const float4 z = {0.f,0.f,0.f,0.f};
#pragma unroll
  for (int i=0;i<16;i++) ((float4*)hr)[tid + i*256] = z;
  __syncthreads();
  if (tid<KSEL){
    float v = candVal[(size_t)r*KSEL+tid];
    hr[candIdx[(size_t)r*KSEL+tid]] = v>0.f ? v : 0.f;
  }
}

extern "C" void kernel_launch(void* const* d_in, const int* in_sizes, int n_in,
                              void* d_out, int out_size, void* d_ws, size_t ws_size,
                              hipStream_t stream)
{
  const float* X     = (const float*)d_in[0];
  const float* tgt   = (const float*)d_in[1];
  const float* Wenc  = (const float*)d_in[2];
  const float* benc  = (const float*)d_in[3];
  const float* Wdec  = (const float*)d_in[4];
  const float* bdec  = (const float*)d_in[5];
  const float* Wskip = (const float*)d_in[6];
  const float* bskip = (const float*)d_in[7];

  float* out     = (float*)d_out;
  float* outhat  = out;
  float* H       = out + (size_t)NT*DO;
  float* lossOut = out + (size_t)NT*DO + (size_t)NT*DH;

  // h-region scratch plan (dead until k_scatter):
  //   [0, 2^28)        : f16 pre-acts
  //   [2^28, ...)      : f16 copies of X, W_enc, W_skip, W_dec^T
  char* hb = (char*)H;
  unsigned short* P      = (unsigned short*)hb;
  char* U                = hb + (size_t)NT*DH*2;
  unsigned short* Xh     = (unsigned short*)U;
  unsigned short* Wench  = (unsigned short*)(U + (size_t)NT*DI*2);
  unsigned short* Wskiph = (unsigned short*)(U + (size_t)NT*DI*2 + (size_t)DH*DI*2);
  unsigned short* WdTh   = (unsigned short*)(U + (size_t)NT*DI*2 + (size_t)DH*DI*2 + (size_t)DO*DI*2);

  // ws: candidate lists must survive the h overwrite
  int*   candIdx    = (int*)d_ws;
  float* candVal    = (float*)((char*)d_ws + (size_t)NT*KSEL*4);
  float* lossPartial= (float*)((char*)d_ws + (size_t)NT*KSEL*8);

  k_cvt<<<NT*DI/8/256, 256, 0, stream>>>(X, Xh, NT*DI/8);
  k_cvt<<<DH*DI/8/256, 256, 0, stream>>>(Wenc, Wench, DH*DI/8);
  k_cvt<<<DO*DI/8/256, 256, 0, stream>>>(Wskip, Wskiph, DO*DI/8);
  k_transpose_cvt<<<dim3(DO/64, DH/64), 256, 0, stream>>>(Wdec, WdTh);

  k_gemm_enc <<<dim3(NT/128, DH/128), 256, 0, stream>>>(Xh, Wench, benc, (void*)P);
  k_topk<<<NT, 256, 0, stream>>>(P, X, Wenc, benc, candIdx, candVal);
  k_gemm_skip<<<dim3(NT/128, DO/128), 256, 0, stream>>>(Xh, Wskiph, bdec, bskip, (void*)outhat);
  k_decode<<<NT, 256, 0, stream>>>(outhat, WdTh, candIdx, candVal, tgt, lossPartial);
  k_lossreduce<<<1, 256, 0, stream>>>(lossPartial, lossOut);
  k_scatter<<<NT, 256, 0, stream>>>(H, candIdx, candVal);
}

// Round 7
// 1757.291 us; speedup vs baseline: 1.1359x; 1.1108x over previous
//
#include <hip/hip_runtime.h>
#include <stdint.h>

#define NT   8192
#define DI   2048
#define DH   16384
#define DO   2048
#define KSEL 64
#define EPS_SEL 0.004f
#define BCAP 256
#define KSTEPS 64   // K=2048 / BK=32 for the 128^2 skip GEMM

typedef _Float16 f16;
typedef f16  f16x8 __attribute__((ext_vector_type(8)));
typedef float f32x4 __attribute__((ext_vector_type(4)));
typedef unsigned short usx8 __attribute__((ext_vector_type(8)));

__device__ __forceinline__ unsigned short f2h_bits(float x){
  f16 h = (f16)x;
  union { f16 h; unsigned short u; } c; c.h = h; return c.u;
}
__device__ __forceinline__ float h_bits2f(unsigned short u){
  union { unsigned short u; f16 h; } c; c.u = u; return (float)c.h;
}

__device__ __forceinline__ void gload16(const void* g, void* lds){
  __builtin_amdgcn_global_load_lds(
    (const __attribute__((address_space(1))) void*)(uintptr_t)g,
    (__attribute__((address_space(3))) void*)(uint32_t)(uintptr_t)lds,
    16, 0, 0);
}

// ---------------- f32 -> f16 convert (vector8) ----------------
__global__ __launch_bounds__(256) void k_cvt(const float* __restrict__ in,
                                             unsigned short* __restrict__ out, int n8)
{
  int i = blockIdx.x*256 + threadIdx.x;
  if (i >= n8) return;
  const float4* p = (const float4*)in + (size_t)i*2;
  float4 a = p[0], b = p[1];
  union { f16 h[8]; usx8 u; } r;
  r.h[0]=(f16)a.x; r.h[1]=(f16)a.y; r.h[2]=(f16)a.z; r.h[3]=(f16)a.w;
  r.h[4]=(f16)b.x; r.h[5]=(f16)b.y; r.h[6]=(f16)b.z; r.h[7]=(f16)b.w;
  ((usx8*)out)[i] = r.u;
}

// ---------------- W_dec [DO][DH] f32 -> WdecT [DH][DO] f16 ----------------
__global__ __launch_bounds__(256) void k_transpose_cvt(const float* __restrict__ W,
                                                       unsigned short* __restrict__ WT)
{
  __shared__ unsigned short t[64][65];
  const int r0 = blockIdx.x*64;   // over DO
  const int c0 = blockIdx.y*64;   // over DH
  const int tid = threadIdx.x;
  const int q = tid >> 6, s = tid & 63;
#pragma unroll
  for (int i=0;i<16;i++){
    int r = q + i*4;
    t[r][s] = f2h_bits(W[(size_t)(r0+r)*DH + c0 + s]);
  }
  __syncthreads();
#pragma unroll
  for (int i=0;i<16;i++){
    int c = q + i*4;
    WT[(size_t)(c0+c)*DO + r0 + s] = t[s][c];
  }
}

// ================= 256^2 8-phase encoder GEMM (m201 template) =================
// C[8192][16384](f16) = A[8192][2048]*B[16384][2048]^T + bias.
// BM=BN=256, BK=64, 512 thr (8 waves, 2M x 4N), LDS 128KB = 2buf x {A,B} x 2half.
// Quadrant walk (mh,nh): (0,0)(0,1)(1,1)(1,0) -> per-phase last-LDS-reads
// A0@1,B1@2,A1@3,B0@4; stages of tile t+2 at phases 2,3,4,5 (+1 margin via the
// double barrier). vmcnt(6) at phases 4,8 only = 3 half-tiles (6 loads) in
// flight; covers every half's first read (derivation in session notes).
// st_16x32 swizzle: read byte lin^=((lin>>9)&1)<<5; stage source chunk
// c^=((c>>5)&1)<<1 (involution stays inside each 4-lane 64B quad -> coalesced).
__global__ __launch_bounds__(512, 2) void k_gemm_enc8(
    const unsigned short* __restrict__ Ap,
    const unsigned short* __restrict__ Bp,
    const float* __restrict__ bias,
    unsigned short* __restrict__ C)
{
  __shared__ unsigned short lds[65536];   // 128 KB
  const int tid  = threadIdx.x;
  const int lane = tid & 63;
  const int wv   = tid >> 6;
  const int wm   = wv >> 2;     // 0..1
  const int wn   = wv & 3;      // 0..3
  const int bm   = blockIdx.x;  // 0..31 (fastest -> B-panel reuse, R5-proven)
  const int bn   = blockIdx.y;  // 0..63
  const int fr   = lane & 15;
  const int fq   = lane >> 4;

  f32x4 acc[8][4];
#pragma unroll
  for (int i=0;i<8;i++)
#pragma unroll
    for (int j=0;j<4;j++) acc[i][j] = (f32x4){0.f,0.f,0.f,0.f};

  f16x8 ar[4][2];   // A frags: 4 mf x 2 ks (current mh)
  f16x8 br[2][2];   // B frags: 2 nf x 2 ks (current nh)

  // u16 offsets: buf*32768 + ab*16384 + half*8192
#define STAGE_HALF(t, ab, h) do { \
    const unsigned short* G_ = (ab) ? Bp : Ap; \
    const int rb_ = ((ab) ? bn : bm)*256 + (h)*128; \
    const int k0_ = (t)*64; \
    const int db_ = ((t)&1)*32768 + (ab)*16384 + (h)*8192; \
    _Pragma("unroll") \
    for (int is_=0; is_<2; ++is_){ \
      const int cw_ = wv*64 + is_*512; \
      const int cl_ = cw_ + lane; \
      const int cs_ = cl_ ^ (((cl_>>5)&1)<<1); \
      gload16(G_ + (size_t)(rb_ + (cs_>>3))*DI + k0_ + (cs_&7)*8, \
              (unsigned short*)lds + db_ + cw_*8); \
    } } while(0)

#define LD_A(buf, mh) do { \
    const int ba_ = (buf)*32768 + (mh)*8192; \
    _Pragma("unroll") \
    for (int mf_=0; mf_<4; ++mf_) \
    _Pragma("unroll") \
    for (int ks_=0; ks_<2; ++ks_){ \
      const int lin_ = (wm*64 + mf_*16 + fr)*128 + (ks_*4 + fq)*16; \
      const int sz_  = lin_ ^ (((lin_>>9)&1)<<5); \
      ar[mf_][ks_] = *(const f16x8*)&lds[ba_ + (sz_>>1)]; \
    } } while(0)

#define LD_B(buf, nh) do { \
    const int bb_ = (buf)*32768 + 16384 + (nh)*8192; \
    _Pragma("unroll") \
    for (int nf_=0; nf_<2; ++nf_) \
    _Pragma("unroll") \
    for (int ks_=0; ks_<2; ++ks_){ \
      const int lin_ = (wn*32 + nf_*16 + fr)*128 + (ks_*4 + fq)*16; \
      const int sz_  = lin_ ^ (((lin_>>9)&1)<<5); \
      br[nf_][ks_] = *(const f16x8*)&lds[bb_ + (sz_>>1)]; \
    } } while(0)

#define MM(mh, nh) do { \
    _Pragma("unroll") \
    for (int mf_=0; mf_<4; ++mf_) \
    _Pragma("unroll") \
    for (int nf_=0; nf_<2; ++nf_) \
    _Pragma("unroll") \
    for (int ks_=0; ks_<2; ++ks_) \
      acc[(mh)*4+mf_][(nh)*2+nf_] = __builtin_amdgcn_mfma_f32_16x16x32_f16( \
          ar[mf_][ks_], br[nf_][ks_], acc[(mh)*4+mf_][(nh)*2+nf_], 0, 0, 0); \
  } while(0)

#define VM6 asm volatile("s_waitcnt vmcnt(6)" ::: "memory")
#define VM0 asm volatile("s_waitcnt vmcnt(0)" ::: "memory")

#define PH(buf, mh, nh, LA_, LB_, STG, VM) do { \
    if (LA_) LD_A(buf, mh); \
    if (LB_) LD_B(buf, nh); \
    STG; \
    VM; \
    __builtin_amdgcn_s_barrier(); \
    asm volatile("s_waitcnt lgkmcnt(0)" ::: "memory"); \
    __builtin_amdgcn_sched_barrier(0); \
    __builtin_amdgcn_s_setprio(1); \
    MM(mh, nh); \
    __builtin_amdgcn_s_setprio(0); \
    __builtin_amdgcn_s_barrier(); \
  } while(0)

  // -------- prologue: tile0 all 4 halves + tile1 {A0,B1,A1} --------
  STAGE_HALF(0,0,0); STAGE_HALF(0,1,1); STAGE_HALF(0,0,1); STAGE_HALF(0,1,0);
  STAGE_HALF(1,0,0); STAGE_HALF(1,1,1); STAGE_HALF(1,0,1);
  asm volatile("s_waitcnt vmcnt(6)" ::: "memory");  // tile0 fully landed
  __builtin_amdgcn_s_barrier();

  // -------- main loop: 15 full iters (tiles 0..29), stages tiles up to 31 ----
  for (int j = 0; j < 15; ++j) {
    const int a = 2*j, b = 2*j+1;
    PH(0, 0,0, 1,1, STAGE_HALF(b,  1,0), (void)0);  // ph1: B0(b)
    PH(0, 0,1, 0,1, STAGE_HALF(a+2,0,0), (void)0);  // ph2: A0(a+2)
    PH(0, 1,1, 1,0, STAGE_HALF(a+2,1,1), (void)0);  // ph3: B1(a+2)
    PH(0, 1,0, 0,1, STAGE_HALF(a+2,0,1), VM6);      // ph4: A1(a+2)
    PH(1, 0,0, 1,1, STAGE_HALF(a+2,1,0), (void)0);  // ph5: B0(a+2)
    PH(1, 0,1, 0,1, STAGE_HALF(b+2,0,0), (void)0);  // ph6: A0(b+2)
    PH(1, 1,1, 1,0, STAGE_HALF(b+2,1,1), (void)0);  // ph7: B1(b+2)
    PH(1, 1,0, 0,1, STAGE_HALF(b+2,0,1), VM6);      // ph8: A1(b+2)
  }
  // -------- last iter: tiles 30,31; only B0(31) left to stage --------
  PH(0, 0,0, 1,1, STAGE_HALF(31,1,0), (void)0);
  PH(0, 0,1, 0,1, (void)0, (void)0);
  PH(0, 1,1, 1,0, (void)0, (void)0);
  PH(0, 1,0, 0,1, (void)0, VM0);                    // drain: tile31 landed
  PH(1, 0,0, 1,1, (void)0, (void)0);
  PH(1, 0,1, 0,1, (void)0, (void)0);
  PH(1, 1,1, 1,0, (void)0, (void)0);
  PH(1, 1,0, 0,1, (void)0, (void)0);

#undef PH
#undef VM6
#undef VM0
#undef MM
#undef LD_B
#undef LD_A
#undef STAGE_HALF

  // -------- epilogue: C/D layout col=lane&15, row=fq*4+q --------
#pragma unroll
  for (int nh=0; nh<2; ++nh)
#pragma unroll
  for (int nf=0; nf<2; ++nf){
    const int col = bn*256 + nh*128 + wn*32 + nf*16 + fr;
    const float bs = bias[col];
#pragma unroll
    for (int mh=0; mh<2; ++mh)
#pragma unroll
    for (int mf=0; mf<4; ++mf){
      const int row0 = bm*256 + mh*128 + wm*64 + mf*16 + fq*4;
#pragma unroll
      for (int q=0; q<4; ++q)
        C[(size_t)(row0+q)*DH + col] = f2h_bits(acc[mh*4+mf][nh*2+nf][q] + bs);
    }
  }
}

// ---------------- 128^2 2-phase GEMM body (kept for the small skip GEMM) -----
template<bool F16OUT>
__device__ __forceinline__ void gemm_body(
    const unsigned short* __restrict__ A,
    const unsigned short* __restrict__ B,
    const float* __restrict__ bias1,
    const float* __restrict__ bias2,
    void* __restrict__ Cout,
    int N, int Kd)
{
  __shared__ unsigned short lA[2][128*32];
  __shared__ unsigned short lB[2][128*32];
  const int tid  = threadIdx.x;
  const int lane = tid & 63;
  const int wv   = tid >> 6;
  const int bm   = blockIdx.x, bn = blockIdx.y;
  const int wm   = wv >> 1, wn = wv & 1;

  f32x4 acc[4][4];
#pragma unroll
  for (int m=0;m<4;m++)
#pragma unroll
    for (int n=0;n<4;n++) acc[m][n] = (f32x4){0.f,0.f,0.f,0.f};

  const int lr  = lane >> 2;
  const int kq4 = lane & 3;
  const unsigned short* gA = A + (size_t)(bm*128 + wv*16 + lr)*Kd + kq4*8;
  const unsigned short* gB = B + (size_t)(bn*128 + wv*16 + lr)*Kd + kq4*8;

#define STAGE(BUF, KS) do { \
    const int _ko = (KS)*32; \
    gload16(gA + _ko,                  &lA[BUF][wv*512]); \
    gload16(gA + _ko + (size_t)64*Kd,  &lA[BUF][2048 + wv*512]); \
    gload16(gB + _ko,                  &lB[BUF][wv*512]); \
    gload16(gB + _ko + (size_t)64*Kd,  &lB[BUF][2048 + wv*512]); \
  } while(0)

#define COMPUTE(BUF) do { \
    const int kq = (lane >> 4) * 8; \
    const int rr = lane & 15; \
    f16x8 af[4], bf[4]; \
    _Pragma("unroll") \
    for (int m=0;m<4;m++) \
      af[m] = *(const f16x8*)&lA[BUF][(wm*64 + m*16 + rr)*32 + kq]; \
    _Pragma("unroll") \
    for (int n=0;n<4;n++) \
      bf[n] = *(const f16x8*)&lB[BUF][(wn*64 + n*16 + rr)*32 + kq]; \
    _Pragma("unroll") \
    for (int m=0;m<4;m++) \
      _Pragma("unroll") \
      for (int n=0;n<4;n++) \
        acc[m][n] = __builtin_amdgcn_mfma_f32_16x16x32_f16(af[m], bf[n], acc[m][n], 0, 0, 0); \
  } while(0)

  STAGE(0, 0);
  __syncthreads();
  for (int e = 0; e < KSTEPS-2; e += 2) {
    STAGE(1, e+1); COMPUTE(0); __syncthreads();
    STAGE(0, e+2); COMPUTE(1); __syncthreads();
  }
  STAGE(1, KSTEPS-1); COMPUTE(0); __syncthreads();
  COMPUTE(1);

#undef STAGE
#undef COMPUTE

  const int rowBase = bm*128 + wm*64 + ((lane>>4)<<2);
  const int colBase = bn*128 + wn*64 + (lane & 15);
#pragma unroll
  for (int n=0;n<4;n++) {
    const int col = colBase + n*16;
    float bs = bias1[col];
    if (bias2) bs += bias2[col];
#pragma unroll
    for (int m=0;m<4;m++) {
#pragma unroll
      for (int q=0;q<4;q++) {
        const int row = rowBase + m*16 + q;
        float v = acc[m][n][q] + bs;
        if (F16OUT) ((unsigned short*)Cout)[(size_t)row*N + col] = f2h_bits(v);
        else        ((float*)Cout)[(size_t)row*N + col] = v;
      }
    }
  }
}

__global__ __launch_bounds__(256) void k_gemm_skip(
    const unsigned short* __restrict__ A, const unsigned short* __restrict__ B,
    const float* __restrict__ bias1, const float* __restrict__ bias2,
    void* __restrict__ Cout)
{
  gemm_body<false>(A, B, bias1, bias2, Cout, DO, DI);
}

// ---------------- exact top-64 per row ----------------
__global__ __launch_bounds__(256) void k_topk(
    const unsigned short* __restrict__ P,
    const float* __restrict__ X,
    const float* __restrict__ Wenc,
    const float* __restrict__ benc,
    int*   __restrict__ candIdx,
    float* __restrict__ candVal)
{
  __shared__ unsigned short row[DH];
  __shared__ unsigned int hist[256];
  __shared__ int inIdx[64];
  __shared__ int bandIdx[BCAP];
  __shared__ double bandVal[BCAP];
  __shared__ unsigned char bandUsed[BCAP];
  __shared__ int s_inCnt, s_bandCnt, s_bsel, s_cntAbove;
  __shared__ float s_T;

  const int r = blockIdx.x;
  const int tid = threadIdx.x;
  const unsigned short* Prow = P + (size_t)r*DH;

  for (int i=tid; i<DH/8; i+=256) ((usx8*)row)[i] = ((const usx8*)Prow)[i];
  hist[tid & 255] = 0;
  if (tid==0){ s_inCnt=0; s_bandCnt=0; }
  __syncthreads();

  for (int i=tid;i<DH;i+=256){
    unsigned short b = row[i];
    unsigned short o = (b & 0x8000) ? (unsigned short)~b : (unsigned short)(b|0x8000);
    atomicAdd(&hist[o>>8], 1u);
  }
  __syncthreads();
  if (tid==0){
    int cum=0, bsel=0;
    for (int h=255; h>=0; h--){
      if (cum + (int)hist[h] >= KSEL){ bsel=h; break; }
      cum += hist[h];
    }
    s_bsel = bsel; s_cntAbove = cum;
  }
  __syncthreads();
  const int bsel = s_bsel; const int cntAbove = s_cntAbove;
  hist[tid & 255] = 0;
  __syncthreads();
  for (int i=tid;i<DH;i+=256){
    unsigned short b = row[i];
    unsigned short o = (b & 0x8000) ? (unsigned short)~b : (unsigned short)(b|0x8000);
    if ((int)(o>>8)==bsel) atomicAdd(&hist[o&0xff],1u);
  }
  __syncthreads();
  if (tid==0){
    int cum = cntAbove, lsel = 0;
    for (int h=255; h>=0; h--){
      if (cum + (int)hist[h] >= KSEL){ lsel=h; break; }
      cum += hist[h];
    }
    unsigned short To = (unsigned short)((bsel<<8) | lsel);
    unsigned short tb = (To & 0x8000) ? (unsigned short)(To ^ 0x8000) : (unsigned short)~To;
    s_T = h_bits2f(tb);
  }
  __syncthreads();
  const float T = s_T;
  const float hiv = T + 2.0f*EPS_SEL, lov = T - 2.0f*EPS_SEL;

  for (int i=tid;i<DH;i+=256){
    float v = h_bits2f(row[i]);
    if (v > hiv){
      int p = atomicAdd(&s_inCnt,1);
      if (p < 64) inIdx[p] = i;
    } else if (v >= lov){
      int p = atomicAdd(&s_bandCnt,1);
      if (p < BCAP) bandIdx[p] = i;
    }
  }
  __syncthreads();
  const int m = s_inCnt < 64 ? s_inCnt : 64;
  const int B = s_bandCnt < BCAP ? s_bandCnt : BCAP;

  const int wv = tid>>6, lane = tid&63;
  const float* Xr = X + (size_t)r*DI;
  for (int b=wv; b<B; b+=4){
    const int j = bandIdx[b];
    const float* Wr = Wenc + (size_t)j*DI;
    double s = 0.0;
    for (int k=lane; k<DI; k+=64)
      s = fma((double)Xr[k], (double)Wr[k], s);
#pragma unroll
    for (int off=32; off>=1; off>>=1) s += __shfl_down(s, off);
    if (lane==0) bandVal[b] = s + (double)benc[j];
  }
  for (int i=tid;i<BCAP;i+=256) bandUsed[i]=0;

  int* ci = candIdx + (size_t)r*KSEL;
  float* cv = candVal + (size_t)r*KSEL;
  for (int t=tid; t<m; t+=256){
    int j = inIdx[t];
    ci[t]=j; cv[t]=h_bits2f(row[j]);
  }
  __syncthreads();
  if (tid==0){
    int need = KSEL - m;
    for (int t=0;t<need;t++){
      double best=-1e300; int bi=0;
      for (int b=0;b<B;b++)
        if (!bandUsed[b] && bandVal[b]>best){ best=bandVal[b]; bi=b; }
      bandUsed[bi]=1;
      ci[m+t]=bandIdx[bi]; cv[m+t]=(float)best;
    }
  }
}

// ---------------- sparse decode + loss partial ----------------
__global__ __launch_bounds__(256) void k_decode(
    float* __restrict__ outhat,
    const unsigned short* __restrict__ WdT,
    const int*   __restrict__ candIdx,
    const float* __restrict__ candVal,
    const float* __restrict__ target,
    float* __restrict__ lossPartial)
{
  __shared__ int   sIdx[KSEL];
  __shared__ float sVal[KSEL];
  __shared__ float wsum[4];
  const int r = blockIdx.x, tid = threadIdx.x;
  if (tid < KSEL){
    sIdx[tid]=candIdx[(size_t)r*KSEL+tid];
    float v=candVal[(size_t)r*KSEL+tid];
    sVal[tid] = v>0.f ? v : 0.f;
  }
  __syncthreads();
  float* orow = outhat + (size_t)r*DO;
  float a[8];
  {
    float4 v0 = *(const float4*)(orow + tid*8);
    float4 v1 = *(const float4*)(orow + tid*8 + 4);
    a[0]=v0.x;a[1]=v0.y;a[2]=v0.z;a[3]=v0.w;a[4]=v1.x;a[5]=v1.y;a[6]=v1.z;a[7]=v1.w;
  }
  for (int c=0;c<KSEL;c++){
    const float v = sVal[c];
    if (v==0.f) continue;
    const f16x8 w = *(const f16x8*)(WdT + (size_t)sIdx[c]*DO + tid*8);
#pragma unroll
    for (int j=0;j<8;j++) a[j] = fmaf(v, (float)w[j], a[j]);
  }
  const float* trow = target + (size_t)r*DO;
  float4 t0 = *(const float4*)(trow + tid*8);
  float4 t1 = *(const float4*)(trow + tid*8 + 4);
  float tt[8] = {t0.x,t0.y,t0.z,t0.w,t1.x,t1.y,t1.z,t1.w};
  float ls = 0.f;
#pragma unroll
  for (int j=0;j<8;j++){ float d = a[j]-tt[j]; ls = fmaf(d,d,ls); }
  {
    float4 v0 = {a[0],a[1],a[2],a[3]}, v1 = {a[4],a[5],a[6],a[7]};
    *(float4*)(orow + tid*8) = v0;
    *(float4*)(orow + tid*8 + 4) = v1;
  }
#pragma unroll
  for (int off=32; off>=1; off>>=1) ls += __shfl_down(ls, off);
  if ((tid&63)==0) wsum[tid>>6]=ls;
  __syncthreads();
  if (tid==0)
    lossPartial[r] = (wsum[0]+wsum[1]+wsum[2]+wsum[3]) * (1.0f/((float)NT*(float)DO));
}

__global__ __launch_bounds__(256) void k_lossreduce(const float* __restrict__ lp,
                                                    float* __restrict__ out)
{
  __shared__ double ws[4];
  double s=0.0;
  for (int i=threadIdx.x;i<NT;i+=256) s += (double)lp[i];
#pragma unroll
  for (int off=32; off>=1; off>>=1) s += __shfl_down(s, off);
  if ((threadIdx.x&63)==0) ws[threadIdx.x>>6]=s;
  __syncthreads();
  if (threadIdx.x==0) *out = (float)(ws[0]+ws[1]+ws[2]+ws[3]);
}

// ---------------- finalize h: zero + scatter ----------------
__global__ __launch_bounds__(256) void k_scatter(
    float* __restrict__ H, const int* __restrict__ candIdx, const float* __restrict__ candVal)
{
  const int r=blockIdx.x, tid=threadIdx.x;
  float* hr = H + (size_t)r*DH;
  const float4 z = {0.f,0.f,0.f,0.f};
#pragma unroll
  for (int i=0;i<16;i++) ((float4*)hr)[tid + i*256] = z;
  __syncthreads();
  if (tid<KSEL){
    float v = candVal[(size_t)r*KSEL+tid];
    hr[candIdx[(size_t)r*KSEL+tid]] = v>0.f ? v : 0.f;
  }
}

extern "C" void kernel_launch(void* const* d_in, const int* in_sizes, int n_in,
                              void* d_out, int out_size, void* d_ws, size_t ws_size,
                              hipStream_t stream)
{
  const float* X     = (const float*)d_in[0];
  const float* tgt   = (const float*)d_in[1];
  const float* Wenc  = (const float*)d_in[2];
  const float* benc  = (const float*)d_in[3];
  const float* Wdec  = (const float*)d_in[4];
  const float* bdec  = (const float*)d_in[5];
  const float* Wskip = (const float*)d_in[6];
  const float* bskip = (const float*)d_in[7];

  float* out     = (float*)d_out;
  float* outhat  = out;
  float* H       = out + (size_t)NT*DO;
  float* lossOut = out + (size_t)NT*DO + (size_t)NT*DH;

  // h-region scratch plan (dead until k_scatter)
  char* hb = (char*)H;
  unsigned short* P      = (unsigned short*)hb;
  char* U                = hb + (size_t)NT*DH*2;
  unsigned short* Xh     = (unsigned short*)U;
  unsigned short* Wench  = (unsigned short*)(U + (size_t)NT*DI*2);
  unsigned short* Wskiph = (unsigned short*)(U + (size_t)NT*DI*2 + (size_t)DH*DI*2);
  unsigned short* WdTh   = (unsigned short*)(U + (size_t)NT*DI*2 + (size_t)DH*DI*2 + (size_t)DO*DI*2);

  int*   candIdx    = (int*)d_ws;
  float* candVal    = (float*)((char*)d_ws + (size_t)NT*KSEL*4);
  float* lossPartial= (float*)((char*)d_ws + (size_t)NT*KSEL*8);

  k_cvt<<<NT*DI/8/256, 256, 0, stream>>>(X, Xh, NT*DI/8);
  k_cvt<<<DH*DI/8/256, 256, 0, stream>>>(Wenc, Wench, DH*DI/8);
  k_cvt<<<DO*DI/8/256, 256, 0, stream>>>(Wskip, Wskiph, DO*DI/8);
  k_transpose_cvt<<<dim3(DO/64, DH/64), 256, 0, stream>>>(Wdec, WdTh);

  k_gemm_enc8<<<dim3(NT/256, DH/256), 512, 0, stream>>>(Xh, Wench, benc, P);
  k_topk<<<NT, 256, 0, stream>>>(P, X, Wenc, benc, candIdx, candVal);
  k_gemm_skip<<<dim3(NT/128, DO/128), 256, 0, stream>>>(Xh, Wskiph, bdec, bskip, (void*)outhat);
  k_decode<<<NT, 256, 0, stream>>>(outhat, WdTh, candIdx, candVal, tgt, lossPartial);
  k_lossreduce<<<1, 256, 0, stream>>>(lossPartial, lossOut);
  k_scatter<<<NT, 256, 0, stream>>>(H, candIdx, candVal);
}

// Round 8
// 1557.539 us; speedup vs baseline: 1.2816x; 1.1282x over previous
//
#include <hip/hip_runtime.h>
#include <stdint.h>

#define NT   8192
#define DI   2048
#define DH   16384
#define DO   2048
#define KSEL 64
#define EPS_SEL 0.004f
#define BCAP 256
#define KSTEPS 64   // K=2048 / BK=32 for the 128^2 skip GEMM

typedef _Float16 f16;
typedef f16  f16x8 __attribute__((ext_vector_type(8)));
typedef float f32x4 __attribute__((ext_vector_type(4)));
typedef unsigned short usx8 __attribute__((ext_vector_type(8)));

__device__ __forceinline__ unsigned short f2h_bits(float x){
  f16 h = (f16)x;
  union { f16 h; unsigned short u; } c; c.h = h; return c.u;
}
__device__ __forceinline__ float h_bits2f(unsigned short u){
  union { unsigned short u; f16 h; } c; c.u = u; return (float)c.h;
}

__device__ __forceinline__ void gload16(const void* g, void* lds){
  __builtin_amdgcn_global_load_lds(
    (const __attribute__((address_space(1))) void*)(uintptr_t)g,
    (__attribute__((address_space(3))) void*)(uint32_t)(uintptr_t)lds,
    16, 0, 0);
}

// ---------------- f32 -> f16 convert (vector8) ----------------
__global__ __launch_bounds__(256) void k_cvt(const float* __restrict__ in,
                                             unsigned short* __restrict__ out, int n8)
{
  int i = blockIdx.x*256 + threadIdx.x;
  if (i >= n8) return;
  const float4* p = (const float4*)in + (size_t)i*2;
  float4 a = p[0], b = p[1];
  union { f16 h[8]; usx8 u; } r;
  r.h[0]=(f16)a.x; r.h[1]=(f16)a.y; r.h[2]=(f16)a.z; r.h[3]=(f16)a.w;
  r.h[4]=(f16)b.x; r.h[5]=(f16)b.y; r.h[6]=(f16)b.z; r.h[7]=(f16)b.w;
  ((usx8*)out)[i] = r.u;
}

// ---------------- W_dec [DO][DH] f32 -> WdecT [DH][DO] f16 ----------------
__global__ __launch_bounds__(256) void k_transpose_cvt(const float* __restrict__ W,
                                                       unsigned short* __restrict__ WT)
{
  __shared__ unsigned short t[64][65];
  const int r0 = blockIdx.x*64;   // over DO
  const int c0 = blockIdx.y*64;   // over DH
  const int tid = threadIdx.x;
  const int q = tid >> 6, s = tid & 63;
#pragma unroll
  for (int i=0;i<16;i++){
    int r = q + i*4;
    t[r][s] = f2h_bits(W[(size_t)(r0+r)*DH + c0 + s]);
  }
  __syncthreads();
#pragma unroll
  for (int i=0;i<16;i++){
    int c = q + i*4;
    WT[(size_t)(c0+c)*DO + r0 + s] = t[s][c];
  }
}

// ================= 256^2 8-phase encoder GEMM (m201 template) =================
__global__ __launch_bounds__(512, 2) void k_gemm_enc8(
    const unsigned short* __restrict__ Ap,
    const unsigned short* __restrict__ Bp,
    const float* __restrict__ bias,
    unsigned short* __restrict__ C)
{
  __shared__ unsigned short lds[65536];   // 128 KB
  const int tid  = threadIdx.x;
  const int lane = tid & 63;
  const int wv   = tid >> 6;
  const int wm   = wv >> 2;     // 0..1
  const int wn   = wv & 3;      // 0..3
  const int bm   = blockIdx.x;  // fastest -> B-panel reuse (R5-proven)
  const int bn   = blockIdx.y;
  const int fr   = lane & 15;
  const int fq   = lane >> 4;

  f32x4 acc[8][4];
#pragma unroll
  for (int i=0;i<8;i++)
#pragma unroll
    for (int j=0;j<4;j++) acc[i][j] = (f32x4){0.f,0.f,0.f,0.f};

  f16x8 ar[4][2];
  f16x8 br[2][2];

#define STAGE_HALF(t, ab, h) do { \
    const unsigned short* G_ = (ab) ? Bp : Ap; \
    const int rb_ = ((ab) ? bn : bm)*256 + (h)*128; \
    const int k0_ = (t)*64; \
    const int db_ = ((t)&1)*32768 + (ab)*16384 + (h)*8192; \
    _Pragma("unroll") \
    for (int is_=0; is_<2; ++is_){ \
      const int cw_ = wv*64 + is_*512; \
      const int cl_ = cw_ + lane; \
      const int cs_ = cl_ ^ (((cl_>>5)&1)<<1); \
      gload16(G_ + (size_t)(rb_ + (cs_>>3))*DI + k0_ + (cs_&7)*8, \
              (unsigned short*)lds + db_ + cw_*8); \
    } } while(0)

#define LD_A(buf, mh) do { \
    const int ba_ = (buf)*32768 + (mh)*8192; \
    _Pragma("unroll") \
    for (int mf_=0; mf_<4; ++mf_) \
    _Pragma("unroll") \
    for (int ks_=0; ks_<2; ++ks_){ \
      const int lin_ = (wm*64 + mf_*16 + fr)*128 + (ks_*4 + fq)*16; \
      const int sz_  = lin_ ^ (((lin_>>9)&1)<<5); \
      ar[mf_][ks_] = *(const f16x8*)&lds[ba_ + (sz_>>1)]; \
    } } while(0)

#define LD_B(buf, nh) do { \
    const int bb_ = (buf)*32768 + 16384 + (nh)*8192; \
    _Pragma("unroll") \
    for (int nf_=0; nf_<2; ++nf_) \
    _Pragma("unroll") \
    for (int ks_=0; ks_<2; ++ks_){ \
      const int lin_ = (wn*32 + nf_*16 + fr)*128 + (ks_*4 + fq)*16; \
      const int sz_  = lin_ ^ (((lin_>>9)&1)<<5); \
      br[nf_][ks_] = *(const f16x8*)&lds[bb_ + (sz_>>1)]; \
    } } while(0)

#define MM(mh, nh) do { \
    _Pragma("unroll") \
    for (int mf_=0; mf_<4; ++mf_) \
    _Pragma("unroll") \
    for (int nf_=0; nf_<2; ++nf_) \
    _Pragma("unroll") \
    for (int ks_=0; ks_<2; ++ks_) \
      acc[(mh)*4+mf_][(nh)*2+nf_] = __builtin_amdgcn_mfma_f32_16x16x32_f16( \
          ar[mf_][ks_], br[nf_][ks_], acc[(mh)*4+mf_][(nh)*2+nf_], 0, 0, 0); \
  } while(0)

#define VM6 asm volatile("s_waitcnt vmcnt(6)" ::: "memory")
#define VM0 asm volatile("s_waitcnt vmcnt(0)" ::: "memory")

#define PH(buf, mh, nh, LA_, LB_, STG, VM) do { \
    if (LA_) LD_A(buf, mh); \
    if (LB_) LD_B(buf, nh); \
    STG; \
    VM; \
    __builtin_amdgcn_s_barrier(); \
    asm volatile("s_waitcnt lgkmcnt(0)" ::: "memory"); \
    __builtin_amdgcn_sched_barrier(0); \
    __builtin_amdgcn_s_setprio(1); \
    MM(mh, nh); \
    __builtin_amdgcn_s_setprio(0); \
    __builtin_amdgcn_s_barrier(); \
  } while(0)

  STAGE_HALF(0,0,0); STAGE_HALF(0,1,1); STAGE_HALF(0,0,1); STAGE_HALF(0,1,0);
  STAGE_HALF(1,0,0); STAGE_HALF(1,1,1); STAGE_HALF(1,0,1);
  asm volatile("s_waitcnt vmcnt(6)" ::: "memory");
  __builtin_amdgcn_s_barrier();

  for (int j = 0; j < 15; ++j) {
    const int a = 2*j, b = 2*j+1;
    PH(0, 0,0, 1,1, STAGE_HALF(b,  1,0), (void)0);
    PH(0, 0,1, 0,1, STAGE_HALF(a+2,0,0), (void)0);
    PH(0, 1,1, 1,0, STAGE_HALF(a+2,1,1), (void)0);
    PH(0, 1,0, 0,1, STAGE_HALF(a+2,0,1), VM6);
    PH(1, 0,0, 1,1, STAGE_HALF(a+2,1,0), (void)0);
    PH(1, 0,1, 0,1, STAGE_HALF(b+2,0,0), (void)0);
    PH(1, 1,1, 1,0, STAGE_HALF(b+2,1,1), (void)0);
    PH(1, 1,0, 0,1, STAGE_HALF(b+2,0,1), VM6);
  }
  PH(0, 0,0, 1,1, STAGE_HALF(31,1,0), (void)0);
  PH(0, 0,1, 0,1, (void)0, (void)0);
  PH(0, 1,1, 1,0, (void)0, (void)0);
  PH(0, 1,0, 0,1, (void)0, VM0);
  PH(1, 0,0, 1,1, (void)0, (void)0);
  PH(1, 0,1, 0,1, (void)0, (void)0);
  PH(1, 1,1, 1,0, (void)0, (void)0);
  PH(1, 1,0, 0,1, (void)0, (void)0);

#undef PH
#undef VM6
#undef VM0
#undef MM
#undef LD_B
#undef LD_A
#undef STAGE_HALF

#pragma unroll
  for (int nh=0; nh<2; ++nh)
#pragma unroll
  for (int nf=0; nf<2; ++nf){
    const int col = bn*256 + nh*128 + wn*32 + nf*16 + fr;
    const float bs = bias[col];
#pragma unroll
    for (int mh=0; mh<2; ++mh)
#pragma unroll
    for (int mf=0; mf<4; ++mf){
      const int row0 = bm*256 + mh*128 + wm*64 + mf*16 + fq*4;
#pragma unroll
      for (int q=0; q<4; ++q)
        C[(size_t)(row0+q)*DH + col] = f2h_bits(acc[mh*4+mf][nh*2+nf][q] + bs);
    }
  }
}

// ---------------- 128^2 2-phase GEMM body (skip GEMM) ----------------
template<bool F16OUT>
__device__ __forceinline__ void gemm_body(
    const unsigned short* __restrict__ A,
    const unsigned short* __restrict__ B,
    const float* __restrict__ bias1,
    const float* __restrict__ bias2,
    void* __restrict__ Cout,
    int N, int Kd)
{
  __shared__ unsigned short lA[2][128*32];
  __shared__ unsigned short lB[2][128*32];
  const int tid  = threadIdx.x;
  const int lane = tid & 63;
  const int wv   = tid >> 6;
  const int bm   = blockIdx.x, bn = blockIdx.y;
  const int wm   = wv >> 1, wn = wv & 1;

  f32x4 acc[4][4];
#pragma unroll
  for (int m=0;m<4;m++)
#pragma unroll
    for (int n=0;n<4;n++) acc[m][n] = (f32x4){0.f,0.f,0.f,0.f};

  const int lr  = lane >> 2;
  const int kq4 = lane & 3;
  const unsigned short* gA = A + (size_t)(bm*128 + wv*16 + lr)*Kd + kq4*8;
  const unsigned short* gB = B + (size_t)(bn*128 + wv*16 + lr)*Kd + kq4*8;

#define STAGE(BUF, KS) do { \
    const int _ko = (KS)*32; \
    gload16(gA + _ko,                  &lA[BUF][wv*512]); \
    gload16(gA + _ko + (size_t)64*Kd,  &lA[BUF][2048 + wv*512]); \
    gload16(gB + _ko,                  &lB[BUF][wv*512]); \
    gload16(gB + _ko + (size_t)64*Kd,  &lB[BUF][2048 + wv*512]); \
  } while(0)

#define COMPUTE(BUF) do { \
    const int kq = (lane >> 4) * 8; \
    const int rr = lane & 15; \
    f16x8 af[4], bf[4]; \
    _Pragma("unroll") \
    for (int m=0;m<4;m++) \
      af[m] = *(const f16x8*)&lA[BUF][(wm*64 + m*16 + rr)*32 + kq]; \
    _Pragma("unroll") \
    for (int n=0;n<4;n++) \
      bf[n] = *(const f16x8*)&lB[BUF][(wn*64 + n*16 + rr)*32 + kq]; \
    _Pragma("unroll") \
    for (int m=0;m<4;m++) \
      _Pragma("unroll") \
      for (int n=0;n<4;n++) \
        acc[m][n] = __builtin_amdgcn_mfma_f32_16x16x32_f16(af[m], bf[n], acc[m][n], 0, 0, 0); \
  } while(0)

  STAGE(0, 0);
  __syncthreads();
  for (int e = 0; e < KSTEPS-2; e += 2) {
    STAGE(1, e+1); COMPUTE(0); __syncthreads();
    STAGE(0, e+2); COMPUTE(1); __syncthreads();
  }
  STAGE(1, KSTEPS-1); COMPUTE(0); __syncthreads();
  COMPUTE(1);

#undef STAGE
#undef COMPUTE

  const int rowBase = bm*128 + wm*64 + ((lane>>4)<<2);
  const int colBase = bn*128 + wn*64 + (lane & 15);
#pragma unroll
  for (int n=0;n<4;n++) {
    const int col = colBase + n*16;
    float bs = bias1[col];
    if (bias2) bs += bias2[col];
#pragma unroll
    for (int m=0;m<4;m++) {
#pragma unroll
      for (int q=0;q<4;q++) {
        const int row = rowBase + m*16 + q;
        float v = acc[m][n][q] + bs;
        if (F16OUT) ((unsigned short*)Cout)[(size_t)row*N + col] = f2h_bits(v);
        else        ((float*)Cout)[(size_t)row*N + col] = v;
      }
    }
  }
}

__global__ __launch_bounds__(256) void k_gemm_skip(
    const unsigned short* __restrict__ A, const unsigned short* __restrict__ B,
    const float* __restrict__ bias1, const float* __restrict__ bias2,
    void* __restrict__ Cout)
{
  gemm_body<false>(A, B, bias1, bias2, Cout, DO, DI);
}

// ---------------- exact top-64 per row (wave-parallel rewrite) ----------------
// Row held in registers (8x usx8). 4 per-wave hist copies. Wave-parallel
// suffix-scan replaces serial 256-bucket loops. Final band selection =
// wave-parallel argmax with register used-masks. Semantics identical to the
// R0-R6 proven version (radix-select T on f16 order-mapped bits; certain-in
// v > T+2eps; band [T-2eps, T+2eps] recomputed in f64 from original f32).
__global__ __launch_bounds__(256) void k_topk(
    const unsigned short* __restrict__ P,
    const float* __restrict__ X,
    const float* __restrict__ Wenc,
    const float* __restrict__ benc,
    int*   __restrict__ candIdx,
    float* __restrict__ candVal)
{
  __shared__ unsigned int hist4[4][256];
  __shared__ unsigned int hist2[256];
  __shared__ int   inIdx[64];
  __shared__ float inVal[64];
  __shared__ int    bandIdx[BCAP];
  __shared__ double bandVal[BCAP];
  __shared__ int s_inCnt, s_bandCnt, s_sel, s_above, s_sel2;

  const int r = blockIdx.x;
  const int tid = threadIdx.x;
  const int wv = tid >> 6, lane = tid & 63;
  const unsigned short* Prow = P + (size_t)r*DH;

#pragma unroll
  for (int k=0;k<4;k++) hist4[k][tid] = 0;
  hist2[tid] = 0;
  if (tid==0){ s_inCnt=0; s_bandCnt=0; }
  __syncthreads();

  // load row into registers + per-wave histogram of order-mapped high byte
  usx8 ch[8];
#pragma unroll
  for (int k=0;k<8;k++) ch[k] = ((const usx8*)Prow)[tid + k*256];
#pragma unroll
  for (int k=0;k<8;k++)
#pragma unroll
    for (int e=0;e<8;e++){
      unsigned short b = ch[k][e];
      unsigned short o = (b & 0x8000) ? (unsigned short)~b : (unsigned short)(b|0x8000);
      atomicAdd(&hist4[wv][o>>8], 1u);
    }
  __syncthreads();
  {
    unsigned int hs = hist4[0][tid]+hist4[1][tid]+hist4[2][tid]+hist4[3][tid];
    hist4[0][tid] = hs;   // each thread owns its column: no cross hazard
  }
  __syncthreads();

  // wave-parallel top-down scan: find bucket where cum-from-top crosses KSEL
  if (tid < 64) {
    const int h0 = 255 - 4*tid;
    unsigned int c0=hist4[0][h0], c1=hist4[0][h0-1], c2=hist4[0][h0-2], c3=hist4[0][h0-3];
    unsigned int s = c0+c1+c2+c3;
    unsigned int Pi = s;
#pragma unroll
    for (int off=1; off<64; off<<=1){
      unsigned int t = __shfl_up(Pi, off);
      if (tid >= off) Pi += t;
    }
    unsigned long long mk = __ballot(Pi >= KSEL);
    int cr = (int)__builtin_ctzll(mk);
    if (tid == cr){
      unsigned int cum = Pi - s;
      unsigned int cc[4] = {c0,c1,c2,c3};
#pragma unroll
      for (int j=0;j<4;j++){
        if (cum + cc[j] >= KSEL){ s_sel = h0-j; s_above = (int)cum; break; }
        cum += cc[j];
      }
    }
  }
  __syncthreads();
  const int bsel = s_sel; const int cntAbove = s_above;

  // pass 2: low-byte hist of bucket-bsel members (from registers)
#pragma unroll
  for (int k=0;k<8;k++)
#pragma unroll
    for (int e=0;e<8;e++){
      unsigned short b = ch[k][e];
      unsigned short o = (b & 0x8000) ? (unsigned short)~b : (unsigned short)(b|0x8000);
      if ((int)(o>>8) == bsel) atomicAdd(&hist2[o & 0xff], 1u);
    }
  __syncthreads();
  {
    const int K2 = KSEL - cntAbove;
    if (tid < 64) {
      const int h0 = 255 - 4*tid;
      unsigned int c0=hist2[h0], c1=hist2[h0-1], c2=hist2[h0-2], c3=hist2[h0-3];
      unsigned int s = c0+c1+c2+c3;
      unsigned int Pi = s;
#pragma unroll
      for (int off=1; off<64; off<<=1){
        unsigned int t = __shfl_up(Pi, off);
        if (tid >= off) Pi += t;
      }
      unsigned long long mk = __ballot(Pi >= (unsigned)K2);
      int cr = (int)__builtin_ctzll(mk);
      if (tid == cr){
        unsigned int cum = Pi - s;
        unsigned int cc[4] = {c0,c1,c2,c3};
#pragma unroll
        for (int j=0;j<4;j++){
          if (cum + cc[j] >= (unsigned)K2){ s_sel2 = h0-j; break; }
          cum += cc[j];
        }
      }
    }
  }
  __syncthreads();

  unsigned short To = (unsigned short)((bsel<<8) | s_sel2);
  unsigned short tb = (To & 0x8000) ? (unsigned short)(To ^ 0x8000) : (unsigned short)~To;
  const float T = h_bits2f(tb);
  const float hiv = T + 2.0f*EPS_SEL, lov = T - 2.0f*EPS_SEL;

  // extraction (from registers): certain-in + ambiguous band
#pragma unroll
  for (int k=0;k<8;k++)
#pragma unroll
    for (int e=0;e<8;e++){
      unsigned short b = ch[k][e];
      float v = h_bits2f(b);
      if (v > hiv){
        int p = atomicAdd(&s_inCnt,1);
        if (p < 64){ inIdx[p] = (tid + k*256)*8 + e; inVal[p] = v; }
      } else if (v >= lov){
        int p = atomicAdd(&s_bandCnt,1);
        if (p < BCAP) bandIdx[p] = (tid + k*256)*8 + e;
      }
    }
  __syncthreads();
  const int m = s_inCnt < 64 ? s_inCnt : 64;
  const int B = s_bandCnt < BCAP ? s_bandCnt : BCAP;

  // exact f64 recompute for ambiguous band (4 waves in parallel)
  const float* Xr = X + (size_t)r*DI;
  for (int b=wv; b<B; b+=4){
    const int j = bandIdx[b];
    const float* Wr = Wenc + (size_t)j*DI;
    double s = 0.0;
    for (int k=lane; k<DI; k+=64)
      s = fma((double)Xr[k], (double)Wr[k], s);
#pragma unroll
    for (int off=32; off>=1; off>>=1) s += __shfl_down(s, off);
    if (lane==0) bandVal[b] = s + (double)benc[j];
  }
  __syncthreads();

  int* ci = candIdx + (size_t)r*KSEL;
  float* cv = candVal + (size_t)r*KSEL;
  for (int t=tid; t<m; t+=256){ ci[t]=inIdx[t]; cv[t]=inVal[t]; }

  // wave-parallel repeated argmax over the band (need = KSEL - m picks)
  const int need = KSEL - m;
  if (tid < 64 && need > 0){
    unsigned int used = 0;   // bit s marks local slot b = tid + 64*s
    for (int t=0;t<need;t++){
      double best = -1.0e300; int bi = -1;
#pragma unroll
      for (int sIt=0;sIt<4;sIt++){
        int b = tid + sIt*64;
        if (b < B && !((used>>sIt)&1)){
          double v = bandVal[b];
          if (v > best){ best=v; bi=b; }
        }
      }
#pragma unroll
      for (int off=32; off>=1; off>>=1){
        double ov = __shfl_down(best, off);
        int    oi = __shfl_down(bi,   off);
        if (ov > best){ best = ov; bi = oi; }
      }
      bi   = __shfl(bi, 0);
      best = __shfl(best, 0);
      if ((bi & 63) == tid) used |= 1u << (bi >> 6);
      if (tid == 0){
        ci[m+t] = bandIdx[bi];
        cv[m+t] = (float)best;
      }
    }
  }
}

// ---------------- sparse decode + loss partial ----------------
__global__ __launch_bounds__(256) void k_decode(
    float* __restrict__ outhat,
    const unsigned short* __restrict__ WdT,
    const int*   __restrict__ candIdx,
    const float* __restrict__ candVal,
    const float* __restrict__ target,
    float* __restrict__ lossPartial)
{
  __shared__ int   sIdx[KSEL];
  __shared__ float sVal[KSEL];
  __shared__ float wsum[4];
  const int r = blockIdx.x, tid = threadIdx.x;
  if (tid < KSEL){
    sIdx[tid]=candIdx[(size_t)r*KSEL+tid];
    float v=candVal[(size_t)r*KSEL+tid];
    sVal[tid] = v>0.f ? v : 0.f;
  }
  __syncthreads();
  float* orow = outhat + (size_t)r*DO;
  float a[8];
  {
    float4 v0 = *(const float4*)(orow + tid*8);
    float4 v1 = *(const float4*)(orow + tid*8 + 4);
    a[0]=v0.x;a[1]=v0.y;a[2]=v0.z;a[3]=v0.w;a[4]=v1.x;a[5]=v1.y;a[6]=v1.z;a[7]=v1.w;
  }
  for (int c=0;c<KSEL;c++){
    const float v = sVal[c];
    if (v==0.f) continue;
    const f16x8 w = *(const f16x8*)(WdT + (size_t)sIdx[c]*DO + tid*8);
#pragma unroll
    for (int j=0;j<8;j++) a[j] = fmaf(v, (float)w[j], a[j]);
  }
  const float* trow = target + (size_t)r*DO;
  float4 t0 = *(const float4*)(trow + tid*8);
  float4 t1 = *(const float4*)(trow + tid*8 + 4);
  float tt[8] = {t0.x,t0.y,t0.z,t0.w,t1.x,t1.y,t1.z,t1.w};
  float ls = 0.f;
#pragma unroll
  for (int j=0;j<8;j++){ float d = a[j]-tt[j]; ls = fmaf(d,d,ls); }
  {
    float4 v0 = {a[0],a[1],a[2],a[3]}, v1 = {a[4],a[5],a[6],a[7]};
    *(float4*)(orow + tid*8) = v0;
    *(float4*)(orow + tid*8 + 4) = v1;
  }
#pragma unroll
  for (int off=32; off>=1; off>>=1) ls += __shfl_down(ls, off);
  if ((tid&63)==0) wsum[tid>>6]=ls;
  __syncthreads();
  if (tid==0)
    lossPartial[r] = (wsum[0]+wsum[1]+wsum[2]+wsum[3]) * (1.0f/((float)NT*(float)DO));
}

__global__ __launch_bounds__(256) void k_lossreduce(const float* __restrict__ lp,
                                                    float* __restrict__ out)
{
  __shared__ double ws[4];
  double s=0.0;
  for (int i=threadIdx.x;i<NT;i+=256) s += (double)lp[i];
#pragma unroll
  for (int off=32; off>=1; off>>=1) s += __shfl_down(s, off);
  if ((threadIdx.x&63)==0) ws[threadIdx.x>>6]=s;
  __syncthreads();
  if (threadIdx.x==0) *out = (float)(ws[0]+ws[1]+ws[2]+ws[3]);
}

// ---------------- finalize h: zero + scatter ----------------
__global__ __launch_bounds__(256) void k_scatter(
    float* __restrict__ H, const int* __restrict__ candIdx, const float* __restrict__ candVal)
{
  const int r=blockIdx.x, tid=threadIdx.x;
  float* hr = H + (size_t)r*DH;
  const float4 z = {0.f,0.f,0.f,0.f};
#pragma unroll
  for (int i=0;i<16;i++) ((float4*)hr)[tid + i*256] = z;
  __syncthreads();
  if (tid<KSEL){
    float v = candVal[(size_t)r*KSEL+tid];
    hr[candIdx[(size_t)r*KSEL+tid]] = v>0.f ? v : 0.f;
  }
}

extern "C" void kernel_launch(void* const* d_in, const int* in_sizes, int n_in,
                              void* d_out, int out_size, void* d_ws, size_t ws_size,
                              hipStream_t stream)
{
  const float* X     = (const float*)d_in[0];
  const float* tgt   = (const float*)d_in[1];
  const float* Wenc  = (const float*)d_in[2];
  const float* benc  = (const float*)d_in[3];
  const float* Wdec  = (const float*)d_in[4];
  const float* bdec  = (const float*)d_in[5];
  const float* Wskip = (const float*)d_in[6];
  const float* bskip = (const float*)d_in[7];

  float* out     = (float*)d_out;
  float* outhat  = out;
  float* H       = out + (size_t)NT*DO;
  float* lossOut = out + (size_t)NT*DO + (size_t)NT*DH;

  // h-region scratch plan (dead until k_scatter)
  char* hb = (char*)H;
  unsigned short* P      = (unsigned short*)hb;
  char* U                = hb + (size_t)NT*DH*2;
  unsigned short* Xh     = (unsigned short*)U;
  unsigned short* Wench  = (unsigned short*)(U + (size_t)NT*DI*2);
  unsigned short* Wskiph = (unsigned short*)(U + (size_t)NT*DI*2 + (size_t)DH*DI*2);
  unsigned short* WdTh   = (unsigned short*)(U + (size_t)NT*DI*2 + (size_t)DH*DI*2 + (size_t)DO*DI*2);

  int*   candIdx    = (int*)d_ws;
  float* candVal    = (float*)((char*)d_ws + (size_t)NT*KSEL*4);
  float* lossPartial= (float*)((char*)d_ws + (size_t)NT*KSEL*8);

  k_cvt<<<NT*DI/8/256, 256, 0, stream>>>(X, Xh, NT*DI/8);
  k_cvt<<<DH*DI/8/256, 256, 0, stream>>>(Wenc, Wench, DH*DI/8);
  k_cvt<<<DO*DI/8/256, 256, 0, stream>>>(Wskip, Wskiph, DO*DI/8);
  k_transpose_cvt<<<dim3(DO/64, DH/64), 256, 0, stream>>>(Wdec, WdTh);

  k_gemm_enc8<<<dim3(NT/256, DH/256), 512, 0, stream>>>(Xh, Wench, benc, P);
  k_topk<<<NT, 256, 0, stream>>>(P, X, Wenc, benc, candIdx, candVal);
  k_gemm_skip<<<dim3(NT/128, DO/128), 256, 0, stream>>>(Xh, Wskiph, bdec, bskip, (void*)outhat);
  k_decode<<<NT, 256, 0, stream>>>(outhat, WdTh, candIdx, candVal, tgt, lossPartial);
  k_lossreduce<<<1, 256, 0, stream>>>(lossPartial, lossOut);
  k_scatter<<<NT, 256, 0, stream>>>(H, candIdx, candVal);
}

// Round 9
// 1517.335 us; speedup vs baseline: 1.3156x; 1.0265x over previous
//
#include <hip/hip_runtime.h>
#include <stdint.h>

#define NT   8192
#define DI   2048
#define DH   16384
#define DO   2048
#define KSEL 64
#define EPS_SEL 0.004f
#define BCAP 256
#define KSTEPS 64   // K=2048 / BK=32 for the 128^2 skip GEMM

typedef _Float16 f16;
typedef f16  f16x8 __attribute__((ext_vector_type(8)));
typedef float f32x4 __attribute__((ext_vector_type(4)));
typedef unsigned short usx8 __attribute__((ext_vector_type(8)));

__device__ __forceinline__ unsigned short f2h_bits(float x){
  f16 h = (f16)x;
  union { f16 h; unsigned short u; } c; c.h = h; return c.u;
}
__device__ __forceinline__ float h_bits2f(unsigned short u){
  union { unsigned short u; f16 h; } c; c.u = u; return (float)c.h;
}

__device__ __forceinline__ void gload16(const void* g, void* lds){
  __builtin_amdgcn_global_load_lds(
    (const __attribute__((address_space(1))) void*)(uintptr_t)g,
    (__attribute__((address_space(3))) void*)(uint32_t)(uintptr_t)lds,
    16, 0, 0);
}

// ---------------- f32 -> f16 convert (vector8) ----------------
__global__ __launch_bounds__(256) void k_cvt(const float* __restrict__ in,
                                             unsigned short* __restrict__ out, int n8)
{
  int i = blockIdx.x*256 + threadIdx.x;
  if (i >= n8) return;
  const float4* p = (const float4*)in + (size_t)i*2;
  float4 a = p[0], b = p[1];
  union { f16 h[8]; usx8 u; } r;
  r.h[0]=(f16)a.x; r.h[1]=(f16)a.y; r.h[2]=(f16)a.z; r.h[3]=(f16)a.w;
  r.h[4]=(f16)b.x; r.h[5]=(f16)b.y; r.h[6]=(f16)b.z; r.h[7]=(f16)b.w;
  ((usx8*)out)[i] = r.u;
}

// ---------------- W_dec [DO][DH] f32 -> WdecT [DH][DO] f16 ----------------
__global__ __launch_bounds__(256) void k_transpose_cvt(const float* __restrict__ W,
                                                       unsigned short* __restrict__ WT)
{
  __shared__ unsigned short t[64][65];
  const int r0 = blockIdx.x*64;   // over DO
  const int c0 = blockIdx.y*64;   // over DH
  const int tid = threadIdx.x;
  const int q = tid >> 6, s = tid & 63;
#pragma unroll
  for (int i=0;i<16;i++){
    int r = q + i*4;
    t[r][s] = f2h_bits(W[(size_t)(r0+r)*DH + c0 + s]);
  }
  __syncthreads();
#pragma unroll
  for (int i=0;i<16;i++){
    int c = q + i*4;
    WT[(size_t)(c0+c)*DO + r0 + s] = t[s][c];
  }
}

// ================= 256^2 8-phase encoder GEMM (m201 template) =================
// R8 change: full 3-bit chunk swizzle (chunk ^= row&7, involution both sides).
// Read: 2 lanes per bank-quad (fr, fr+8) -> 2-way = free. Stage: XOR constant
// within each 8-lane row group keeps every 4-lane quad in one aligned 64B
// segment -> coalescing preserved (R2-proven class).
__global__ __launch_bounds__(512, 2) void k_gemm_enc8(
    const unsigned short* __restrict__ Ap,
    const unsigned short* __restrict__ Bp,
    const float* __restrict__ bias,
    unsigned short* __restrict__ C)
{
  __shared__ unsigned short lds[65536];   // 128 KB
  const int tid  = threadIdx.x;
  const int lane = tid & 63;
  const int wv   = tid >> 6;
  const int wm   = wv >> 2;     // 0..1
  const int wn   = wv & 3;      // 0..3
  const int bm   = blockIdx.x;  // fastest -> B-panel reuse (R5-proven)
  const int bn   = blockIdx.y;
  const int fr   = lane & 15;
  const int fq   = lane >> 4;

  f32x4 acc[8][4];
#pragma unroll
  for (int i=0;i<8;i++)
#pragma unroll
    for (int j=0;j<4;j++) acc[i][j] = (f32x4){0.f,0.f,0.f,0.f};

  f16x8 ar[4][2];
  f16x8 br[2][2];

#define STAGE_HALF(t, ab, h) do { \
    const unsigned short* G_ = (ab) ? Bp : Ap; \
    const int rb_ = ((ab) ? bn : bm)*256 + (h)*128; \
    const int k0_ = (t)*64; \
    const int db_ = ((t)&1)*32768 + (ab)*16384 + (h)*8192; \
    _Pragma("unroll") \
    for (int is_=0; is_<2; ++is_){ \
      const int cw_ = wv*64 + is_*512; \
      const int cl_ = cw_ + lane; \
      const int cs_ = cl_ ^ ((cl_>>3)&7); \
      gload16(G_ + (size_t)(rb_ + (cs_>>3))*DI + k0_ + (cs_&7)*8, \
              (unsigned short*)lds + db_ + cw_*8); \
    } } while(0)

#define LD_A(buf, mh) do { \
    const int ba_ = (buf)*32768 + (mh)*8192; \
    _Pragma("unroll") \
    for (int mf_=0; mf_<4; ++mf_) \
    _Pragma("unroll") \
    for (int ks_=0; ks_<2; ++ks_){ \
      const int lin_ = (wm*64 + mf_*16 + fr)*128 + (ks_*4 + fq)*16; \
      const int sz_  = lin_ ^ ((((lin_>>7)&7))<<4); \
      ar[mf_][ks_] = *(const f16x8*)&lds[ba_ + (sz_>>1)]; \
    } } while(0)

#define LD_B(buf, nh) do { \
    const int bb_ = (buf)*32768 + 16384 + (nh)*8192; \
    _Pragma("unroll") \
    for (int nf_=0; nf_<2; ++nf_) \
    _Pragma("unroll") \
    for (int ks_=0; ks_<2; ++ks_){ \
      const int lin_ = (wn*32 + nf_*16 + fr)*128 + (ks_*4 + fq)*16; \
      const int sz_  = lin_ ^ ((((lin_>>7)&7))<<4); \
      br[nf_][ks_] = *(const f16x8*)&lds[bb_ + (sz_>>1)]; \
    } } while(0)

#define MM(mh, nh) do { \
    _Pragma("unroll") \
    for (int mf_=0; mf_<4; ++mf_) \
    _Pragma("unroll") \
    for (int nf_=0; nf_<2; ++nf_) \
    _Pragma("unroll") \
    for (int ks_=0; ks_<2; ++ks_) \
      acc[(mh)*4+mf_][(nh)*2+nf_] = __builtin_amdgcn_mfma_f32_16x16x32_f16( \
          ar[mf_][ks_], br[nf_][ks_], acc[(mh)*4+mf_][(nh)*2+nf_], 0, 0, 0); \
  } while(0)

#define VM6 asm volatile("s_waitcnt vmcnt(6)" ::: "memory")
#define VM0 asm volatile("s_waitcnt vmcnt(0)" ::: "memory")

#define PH(buf, mh, nh, LA_, LB_, STG, VM) do { \
    if (LA_) LD_A(buf, mh); \
    if (LB_) LD_B(buf, nh); \
    STG; \
    VM; \
    __builtin_amdgcn_s_barrier(); \
    asm volatile("s_waitcnt lgkmcnt(0)" ::: "memory"); \
    __builtin_amdgcn_sched_barrier(0); \
    __builtin_amdgcn_s_setprio(1); \
    MM(mh, nh); \
    __builtin_amdgcn_s_setprio(0); \
    __builtin_amdgcn_s_barrier(); \
  } while(0)

  STAGE_HALF(0,0,0); STAGE_HALF(0,1,1); STAGE_HALF(0,0,1); STAGE_HALF(0,1,0);
  STAGE_HALF(1,0,0); STAGE_HALF(1,1,1); STAGE_HALF(1,0,1);
  asm volatile("s_waitcnt vmcnt(6)" ::: "memory");
  __builtin_amdgcn_s_barrier();

  for (int j = 0; j < 15; ++j) {
    const int a = 2*j, b = 2*j+1;
    PH(0, 0,0, 1,1, STAGE_HALF(b,  1,0), (void)0);
    PH(0, 0,1, 0,1, STAGE_HALF(a+2,0,0), (void)0);
    PH(0, 1,1, 1,0, STAGE_HALF(a+2,1,1), (void)0);
    PH(0, 1,0, 0,1, STAGE_HALF(a+2,0,1), VM6);
    PH(1, 0,0, 1,1, STAGE_HALF(a+2,1,0), (void)0);
    PH(1, 0,1, 0,1, STAGE_HALF(b+2,0,0), (void)0);
    PH(1, 1,1, 1,0, STAGE_HALF(b+2,1,1), (void)0);
    PH(1, 1,0, 0,1, STAGE_HALF(b+2,0,1), VM6);
  }
  PH(0, 0,0, 1,1, STAGE_HALF(31,1,0), (void)0);
  PH(0, 0,1, 0,1, (void)0, (void)0);
  PH(0, 1,1, 1,0, (void)0, (void)0);
  PH(0, 1,0, 0,1, (void)0, VM0);
  PH(1, 0,0, 1,1, (void)0, (void)0);
  PH(1, 0,1, 0,1, (void)0, (void)0);
  PH(1, 1,1, 1,0, (void)0, (void)0);
  PH(1, 1,0, 0,1, (void)0, (void)0);

#undef PH
#undef VM6
#undef VM0
#undef MM
#undef LD_B
#undef LD_A
#undef STAGE_HALF

#pragma unroll
  for (int nh=0; nh<2; ++nh)
#pragma unroll
  for (int nf=0; nf<2; ++nf){
    const int col = bn*256 + nh*128 + wn*32 + nf*16 + fr;
    const float bs = bias[col];
#pragma unroll
    for (int mh=0; mh<2; ++mh)
#pragma unroll
    for (int mf=0; mf<4; ++mf){
      const int row0 = bm*256 + mh*128 + wm*64 + mf*16 + fq*4;
#pragma unroll
      for (int q=0; q<4; ++q)
        C[(size_t)(row0+q)*DH + col] = f2h_bits(acc[mh*4+mf][nh*2+nf][q] + bs);
    }
  }
}

// ---------------- 128^2 2-phase GEMM body (skip GEMM) ----------------
template<bool F16OUT>
__device__ __forceinline__ void gemm_body(
    const unsigned short* __restrict__ A,
    const unsigned short* __restrict__ B,
    const float* __restrict__ bias1,
    const float* __restrict__ bias2,
    void* __restrict__ Cout,
    int N, int Kd)
{
  __shared__ unsigned short lA[2][128*32];
  __shared__ unsigned short lB[2][128*32];
  const int tid  = threadIdx.x;
  const int lane = tid & 63;
  const int wv   = tid >> 6;
  const int bm   = blockIdx.x, bn = blockIdx.y;
  const int wm   = wv >> 1, wn = wv & 1;

  f32x4 acc[4][4];
#pragma unroll
  for (int m=0;m<4;m++)
#pragma unroll
    for (int n=0;n<4;n++) acc[m][n] = (f32x4){0.f,0.f,0.f,0.f};

  const int lr  = lane >> 2;
  const int kq4 = lane & 3;
  const unsigned short* gA = A + (size_t)(bm*128 + wv*16 + lr)*Kd + kq4*8;
  const unsigned short* gB = B + (size_t)(bn*128 + wv*16 + lr)*Kd + kq4*8;

#define STAGE(BUF, KS) do { \
    const int _ko = (KS)*32; \
    gload16(gA + _ko,                  &lA[BUF][wv*512]); \
    gload16(gA + _ko + (size_t)64*Kd,  &lA[BUF][2048 + wv*512]); \
    gload16(gB + _ko,                  &lB[BUF][wv*512]); \
    gload16(gB + _ko + (size_t)64*Kd,  &lB[BUF][2048 + wv*512]); \
  } while(0)

#define COMPUTE(BUF) do { \
    const int kq = (lane >> 4) * 8; \
    const int rr = lane & 15; \
    f16x8 af[4], bf[4]; \
    _Pragma("unroll") \
    for (int m=0;m<4;m++) \
      af[m] = *(const f16x8*)&lA[BUF][(wm*64 + m*16 + rr)*32 + kq]; \
    _Pragma("unroll") \
    for (int n=0;n<4;n++) \
      bf[n] = *(const f16x8*)&lB[BUF][(wn*64 + n*16 + rr)*32 + kq]; \
    _Pragma("unroll") \
    for (int m=0;m<4;m++) \
      _Pragma("unroll") \
      for (int n=0;n<4;n++) \
        acc[m][n] = __builtin_amdgcn_mfma_f32_16x16x32_f16(af[m], bf[n], acc[m][n], 0, 0, 0); \
  } while(0)

  STAGE(0, 0);
  __syncthreads();
  for (int e = 0; e < KSTEPS-2; e += 2) {
    STAGE(1, e+1); COMPUTE(0); __syncthreads();
    STAGE(0, e+2); COMPUTE(1); __syncthreads();
  }
  STAGE(1, KSTEPS-1); COMPUTE(0); __syncthreads();
  COMPUTE(1);

#undef STAGE
#undef COMPUTE

  const int rowBase = bm*128 + wm*64 + ((lane>>4)<<2);
  const int colBase = bn*128 + wn*64 + (lane & 15);
#pragma unroll
  for (int n=0;n<4;n++) {
    const int col = colBase + n*16;
    float bs = bias1[col];
    if (bias2) bs += bias2[col];
#pragma unroll
    for (int m=0;m<4;m++) {
#pragma unroll
      for (int q=0;q<4;q++) {
        const int row = rowBase + m*16 + q;
        float v = acc[m][n][q] + bs;
        if (F16OUT) ((unsigned short*)Cout)[(size_t)row*N + col] = f2h_bits(v);
        else        ((float*)Cout)[(size_t)row*N + col] = v;
      }
    }
  }
}

__global__ __launch_bounds__(256) void k_gemm_skip(
    const unsigned short* __restrict__ A, const unsigned short* __restrict__ B,
    const float* __restrict__ bias1, const float* __restrict__ bias2,
    void* __restrict__ Cout)
{
  gemm_body<false>(A, B, bias1, bias2, Cout, DO, DI);
}

// ---------------- exact top-64 per row (wave-parallel, R7-proven) ----------------
__global__ __launch_bounds__(256) void k_topk(
    const unsigned short* __restrict__ P,
    const float* __restrict__ X,
    const float* __restrict__ Wenc,
    const float* __restrict__ benc,
    int*   __restrict__ candIdx,
    float* __restrict__ candVal)
{
  __shared__ unsigned int hist4[4][256];
  __shared__ unsigned int hist2[256];
  __shared__ int   inIdx[64];
  __shared__ float inVal[64];
  __shared__ int    bandIdx[BCAP];
  __shared__ double bandVal[BCAP];
  __shared__ int s_inCnt, s_bandCnt, s_sel, s_above, s_sel2;

  const int r = blockIdx.x;
  const int tid = threadIdx.x;
  const int wv = tid >> 6, lane = tid & 63;
  const unsigned short* Prow = P + (size_t)r*DH;

#pragma unroll
  for (int k=0;k<4;k++) hist4[k][tid] = 0;
  hist2[tid] = 0;
  if (tid==0){ s_inCnt=0; s_bandCnt=0; }
  __syncthreads();

  usx8 ch[8];
#pragma unroll
  for (int k=0;k<8;k++) ch[k] = ((const usx8*)Prow)[tid + k*256];
#pragma unroll
  for (int k=0;k<8;k++)
#pragma unroll
    for (int e=0;e<8;e++){
      unsigned short b = ch[k][e];
      unsigned short o = (b & 0x8000) ? (unsigned short)~b : (unsigned short)(b|0x8000);
      atomicAdd(&hist4[wv][o>>8], 1u);
    }
  __syncthreads();
  {
    unsigned int hs = hist4[0][tid]+hist4[1][tid]+hist4[2][tid]+hist4[3][tid];
    hist4[0][tid] = hs;
  }
  __syncthreads();

  if (tid < 64) {
    const int h0 = 255 - 4*tid;
    unsigned int c0=hist4[0][h0], c1=hist4[0][h0-1], c2=hist4[0][h0-2], c3=hist4[0][h0-3];
    unsigned int s = c0+c1+c2+c3;
    unsigned int Pi = s;
#pragma unroll
    for (int off=1; off<64; off<<=1){
      unsigned int t = __shfl_up(Pi, off);
      if (tid >= off) Pi += t;
    }
    unsigned long long mk = __ballot(Pi >= KSEL);
    int cr = (int)__builtin_ctzll(mk);
    if (tid == cr){
      unsigned int cum = Pi - s;
      unsigned int cc[4] = {c0,c1,c2,c3};
#pragma unroll
      for (int j=0;j<4;j++){
        if (cum + cc[j] >= KSEL){ s_sel = h0-j; s_above = (int)cum; break; }
        cum += cc[j];
      }
    }
  }
  __syncthreads();
  const int bsel = s_sel; const int cntAbove = s_above;

#pragma unroll
  for (int k=0;k<8;k++)
#pragma unroll
    for (int e=0;e<8;e++){
      unsigned short b = ch[k][e];
      unsigned short o = (b & 0x8000) ? (unsigned short)~b : (unsigned short)(b|0x8000);
      if ((int)(o>>8) == bsel) atomicAdd(&hist2[o & 0xff], 1u);
    }
  __syncthreads();
  {
    const int K2 = KSEL - cntAbove;
    if (tid < 64) {
      const int h0 = 255 - 4*tid;
      unsigned int c0=hist2[h0], c1=hist2[h0-1], c2=hist2[h0-2], c3=hist2[h0-3];
      unsigned int s = c0+c1+c2+c3;
      unsigned int Pi = s;
#pragma unroll
      for (int off=1; off<64; off<<=1){
        unsigned int t = __shfl_up(Pi, off);
        if (tid >= off) Pi += t;
      }
      unsigned long long mk = __ballot(Pi >= (unsigned)K2);
      int cr = (int)__builtin_ctzll(mk);
      if (tid == cr){
        unsigned int cum = Pi - s;
        unsigned int cc[4] = {c0,c1,c2,c3};
#pragma unroll
        for (int j=0;j<4;j++){
          if (cum + cc[j] >= (unsigned)K2){ s_sel2 = h0-j; break; }
          cum += cc[j];
        }
      }
    }
  }
  __syncthreads();

  unsigned short To = (unsigned short)((bsel<<8) | s_sel2);
  unsigned short tb = (To & 0x8000) ? (unsigned short)(To ^ 0x8000) : (unsigned short)~To;
  const float T = h_bits2f(tb);
  const float hiv = T + 2.0f*EPS_SEL, lov = T - 2.0f*EPS_SEL;

#pragma unroll
  for (int k=0;k<8;k++)
#pragma unroll
    for (int e=0;e<8;e++){
      unsigned short b = ch[k][e];
      float v = h_bits2f(b);
      if (v > hiv){
        int p = atomicAdd(&s_inCnt,1);
        if (p < 64){ inIdx[p] = (tid + k*256)*8 + e; inVal[p] = v; }
      } else if (v >= lov){
        int p = atomicAdd(&s_bandCnt,1);
        if (p < BCAP) bandIdx[p] = (tid + k*256)*8 + e;
      }
    }
  __syncthreads();
  const int m = s_inCnt < 64 ? s_inCnt : 64;
  const int B = s_bandCnt < BCAP ? s_bandCnt : BCAP;

  const float* Xr = X + (size_t)r*DI;
  for (int b=wv; b<B; b+=4){
    const int j = bandIdx[b];
    const float* Wr = Wenc + (size_t)j*DI;
    double s = 0.0;
    for (int k=lane; k<DI; k+=64)
      s = fma((double)Xr[k], (double)Wr[k], s);
#pragma unroll
    for (int off=32; off>=1; off>>=1) s += __shfl_down(s, off);
    if (lane==0) bandVal[b] = s + (double)benc[j];
  }
  __syncthreads();

  int* ci = candIdx + (size_t)r*KSEL;
  float* cv = candVal + (size_t)r*KSEL;
  for (int t=tid; t<m; t+=256){ ci[t]=inIdx[t]; cv[t]=inVal[t]; }

  const int need = KSEL - m;
  if (tid < 64 && need > 0){
    unsigned int used = 0;
    for (int t=0;t<need;t++){
      double best = -1.0e300; int bi = -1;
#pragma unroll
      for (int sIt=0;sIt<4;sIt++){
        int b = tid + sIt*64;
        if (b < B && !((used>>sIt)&1)){
          double v = bandVal[b];
          if (v > best){ best=v; bi=b; }
        }
      }
#pragma unroll
      for (int off=32; off>=1; off>>=1){
        double ov = __shfl_down(best, off);
        int    oi = __shfl_down(bi,   off);
        if (ov > best){ best = ov; bi = oi; }
      }
      bi   = __shfl(bi, 0);
      best = __shfl(best, 0);
      if ((bi & 63) == tid) used |= 1u << (bi >> 6);
      if (tid == 0){
        ci[m+t] = bandIdx[bi];
        cv[m+t] = (float)best;
      }
    }
  }
}

// ---------------- sparse decode + loss partial ----------------
__global__ __launch_bounds__(256) void k_decode(
    float* __restrict__ outhat,
    const unsigned short* __restrict__ WdT,
    const int*   __restrict__ candIdx,
    const float* __restrict__ candVal,
    const float* __restrict__ target,
    float* __restrict__ lossPartial)
{
  __shared__ int   sIdx[KSEL];
  __shared__ float sVal[KSEL];
  __shared__ float wsum[4];
  const int r = blockIdx.x, tid = threadIdx.x;
  if (tid < KSEL){
    sIdx[tid]=candIdx[(size_t)r*KSEL+tid];
    float v=candVal[(size_t)r*KSEL+tid];
    sVal[tid] = v>0.f ? v : 0.f;
  }
  __syncthreads();
  float* orow = outhat + (size_t)r*DO;
  float a[8];
  {
    float4 v0 = *(const float4*)(orow + tid*8);
    float4 v1 = *(const float4*)(orow + tid*8 + 4);
    a[0]=v0.x;a[1]=v0.y;a[2]=v0.z;a[3]=v0.w;a[4]=v1.x;a[5]=v1.y;a[6]=v1.z;a[7]=v1.w;
  }
  for (int c=0;c<KSEL;c++){
    const float v = sVal[c];
    if (v==0.f) continue;
    const f16x8 w = *(const f16x8*)(WdT + (size_t)sIdx[c]*DO + tid*8);
#pragma unroll
    for (int j=0;j<8;j++) a[j] = fmaf(v, (float)w[j], a[j]);
  }
  const float* trow = target + (size_t)r*DO;
  float4 t0 = *(const float4*)(trow + tid*8);
  float4 t1 = *(const float4*)(trow + tid*8 + 4);
  float tt[8] = {t0.x,t0.y,t0.z,t0.w,t1.x,t1.y,t1.z,t1.w};
  float ls = 0.f;
#pragma unroll
  for (int j=0;j<8;j++){ float d = a[j]-tt[j]; ls = fmaf(d,d,ls); }
  {
    float4 v0 = {a[0],a[1],a[2],a[3]}, v1 = {a[4],a[5],a[6],a[7]};
    *(float4*)(orow + tid*8) = v0;
    *(float4*)(orow + tid*8 + 4) = v1;
  }
#pragma unroll
  for (int off=32; off>=1; off>>=1) ls += __shfl_down(ls, off);
  if ((tid&63)==0) wsum[tid>>6]=ls;
  __syncthreads();
  if (tid==0)
    lossPartial[r] = (wsum[0]+wsum[1]+wsum[2]+wsum[3]) * (1.0f/((float)NT*(float)DO));
}

__global__ __launch_bounds__(256) void k_lossreduce(const float* __restrict__ lp,
                                                    float* __restrict__ out)
{
  __shared__ double ws[4];
  double s=0.0;
  for (int i=threadIdx.x;i<NT;i+=256) s += (double)lp[i];
#pragma unroll
  for (int off=32; off>=1; off>>=1) s += __shfl_down(s, off);
  if ((threadIdx.x&63)==0) ws[threadIdx.x>>6]=s;
  __syncthreads();
  if (threadIdx.x==0) *out = (float)(ws[0]+ws[1]+ws[2]+ws[3]);
}

// ---------------- finalize h: zero + scatter ----------------
__global__ __launch_bounds__(256) void k_scatter(
    float* __restrict__ H, const int* __restrict__ candIdx, const float* __restrict__ candVal)
{
  const int r=blockIdx.x, tid=threadIdx.x;
  float* hr = H + (size_t)r*DH;
  const float4 z = {0.f,0.f,0.f,0.f};
#pragma unroll
  for (int i=0;i<16;i++) ((float4*)hr)[tid + i*256] = z;
  __syncthreads();
  if (tid<KSEL){
    float v = candVal[(size_t)r*KSEL+tid];
    hr[candIdx[(size_t)r*KSEL+tid]] = v>0.f ? v : 0.f;
  }
}

extern "C" void kernel_launch(void* const* d_in, const int* in_sizes, int n_in,
                              void* d_out, int out_size, void* d_ws, size_t ws_size,
                              hipStream_t stream)
{
  const float* X     = (const float*)d_in[0];
  const float* tgt   = (const float*)d_in[1];
  const float* Wenc  = (const float*)d_in[2];
  const float* benc  = (const float*)d_in[3];
  const float* Wdec  = (const float*)d_in[4];
  const float* bdec  = (const float*)d_in[5];
  const float* Wskip = (const float*)d_in[6];
  const float* bskip = (const float*)d_in[7];

  float* out     = (float*)d_out;
  float* outhat  = out;
  float* H       = out + (size_t)NT*DO;
  float* lossOut = out + (size_t)NT*DO + (size_t)NT*DH;

  // h-region scratch plan (dead until k_scatter)
  char* hb = (char*)H;
  unsigned short* P      = (unsigned short*)hb;
  char* U                = hb + (size_t)NT*DH*2;
  unsigned short* Xh     = (unsigned short*)U;
  unsigned short* Wench  = (unsigned short*)(U + (size_t)NT*DI*2);
  unsigned short* Wskiph = (unsigned short*)(U + (size_t)NT*DI*2 + (size_t)DH*DI*2);
  unsigned short* WdTh   = (unsigned short*)(U + (size_t)NT*DI*2 + (size_t)DH*DI*2 + (size_t)DO*DI*2);

  int*   candIdx    = (int*)d_ws;
  float* candVal    = (float*)((char*)d_ws + (size_t)NT*KSEL*4);
  float* lossPartial= (float*)((char*)d_ws + (size_t)NT*KSEL*8);

  k_cvt<<<NT*DI/8/256, 256, 0, stream>>>(X, Xh, NT*DI/8);
  k_cvt<<<DH*DI/8/256, 256, 0, stream>>>(Wenc, Wench, DH*DI/8);
  k_cvt<<<DO*DI/8/256, 256, 0, stream>>>(Wskip, Wskiph, DO*DI/8);
  k_transpose_cvt<<<dim3(DO/64, DH/64), 256, 0, stream>>>(Wdec, WdTh);

  k_gemm_enc8<<<dim3(NT/256, DH/256), 512, 0, stream>>>(Xh, Wench, benc, P);
  k_topk<<<NT, 256, 0, stream>>>(P, X, Wenc, benc, candIdx, candVal);
  k_gemm_skip<<<dim3(NT/128, DO/128), 256, 0, stream>>>(Xh, Wskiph, bdec, bskip, (void*)outhat);
  k_decode<<<NT, 256, 0, stream>>>(outhat, WdTh, candIdx, candVal, tgt, lossPartial);
  k_lossreduce<<<1, 256, 0, stream>>>(lossPartial, lossOut);
  k_scatter<<<NT, 256, 0, stream>>>(H, candIdx, candVal);
}